// Round 10
// baseline (898.708 us; speedup 1.0000x reference)
//
#include <hip/hip_runtime.h>
#include <hip/hip_bf16.h>

// GraphSAGE 3-layer: 40 -> 64 -> 128 -> 3, mean aggregation over fixed edges.
// R10: fix R8/R9 crash root cause — k_bucket's blockIdx decomposition made 8
// blocks process the SAME edge chunk (no dst filter) -> 8x deg, cursor
// overflow, OOB csr writes, device fault. Now each block owns a distinct
// 782-edge chunk; part = blockIdx&7 is only the block's XCD tag for bucket
// selection. pairs still aliases A2cat (dead before A2cat written).

static constexpr int NN = 100000;
static constexpr int EE = 1600000;
static constexpr int NB = (NN + 255) / 256;   // 391 scan blocks
static constexpr int NRANGE = 64;
static constexpr int RSIZE = (NN + NRANGE - 1) / NRANGE;   // 1563
static constexpr int NBUCKET = 8 * NRANGE;                 // 512
static constexpr int CAP = 4096;     // per-bucket capacity (mean 3125, ~17 sigma)
static constexpr int BUCKET_BLOCKS = 2048;
static constexpr int BCHUNK = (EE + BUCKET_BLOCKS - 1) / BUCKET_BLOCKS;  // 782

typedef __attribute__((ext_vector_type(8))) short short8;
typedef __attribute__((ext_vector_type(4))) float f32x4;

__device__ __forceinline__ float bf2f(unsigned short u) {
    union { unsigned int i; float f; } c; c.i = ((unsigned int)u) << 16; return c.f;
}
__device__ __forceinline__ unsigned short f2bf(float f) {
    union { float f; unsigned int i; } c; c.f = f;
    unsigned int x = c.i;
    return (unsigned short)((x + 0x7fffu + ((x >> 16) & 1u)) >> 16);   // RNE
}

// ---------------- phase 1: bucket edges by (xcd, dst-range), count degrees ----------------
// Each block owns a DISTINCT chunk of edges (read once). part = blockIdx&7 is
// the block's own XCD (round-robin dispatch heuristic): appends go to that
// XCD's bucket family, keeping the 64B append tails XCD-local.
__global__ __launch_bounds__(256) void k_bucket(const int* __restrict__ src, const int* __restrict__ dst,
                                                int* __restrict__ deg, int* __restrict__ pcur,
                                                int2* __restrict__ pairs) {
    const int part = blockIdx.x & 7;
    const int e0 = blockIdx.x * BCHUNK;
    const int e1 = (e0 + BCHUNK < EE) ? e0 + BCHUNK : EE;
    for (int e = e0 + threadIdx.x; e < e1; e += 256) {
        int d = dst[e];
        int s = src[e];
        atomicAdd(&deg[d], 1);
        int r = d / RSIZE;                      // const-divide -> magic mul
        int b = (part << 6) | r;
        int pos = atomicAdd(&pcur[b], 1);
        if (pos < CAP) pairs[(size_t)b * CAP + pos] = make_int2(s, d);
    }
}

// ---------------- phase 2: scatter buckets into CSR (XCD-local csr window) ----------------
__global__ __launch_bounds__(256) void k_scatter(const int2* __restrict__ pairs, const int* __restrict__ pcur,
                                                 const int* __restrict__ row_start, int* __restrict__ cursor,
                                                 int* __restrict__ csr_src) {
    const int r = blockIdx.x & 63;              // dst range; XCD = r%8 = blockIdx%8
    const int j = blockIdx.x >> 6;              // 0..15 sub-chunk
    for (int p = 0; p < 8; ++p) {
        int b = (p << 6) | r;
        int len = pcur[b];
        if (len > CAP) len = CAP;
        int i0 = (len * j) >> 4;
        int i1 = (len * (j + 1)) >> 4;
        const int2* base = pairs + (size_t)b * CAP;
        for (int i = i0 + threadIdx.x; i < i1; i += 256) {
            int2 e = base[i];
            int pos = atomicAdd(&cursor[e.y], 1);
            csr_src[row_start[e.y] + pos] = e.x;
        }
    }
}

// ---------------- hierarchical scan: block sums ----------------
__global__ __launch_bounds__(256) void k_bsum(const int* __restrict__ deg, int* __restrict__ bsum) {
    int i = blockIdx.x * 256 + threadIdx.x;
    int v = (i < NN) ? deg[i] : 0;
    int lane = threadIdx.x & 63, wid = threadIdx.x >> 6;
#pragma unroll
    for (int d = 32; d; d >>= 1) v += __shfl_down(v, d, 64);
    __shared__ int wsum[4];
    if (lane == 0) wsum[wid] = v;
    __syncthreads();
    if (threadIdx.x == 0) bsum[blockIdx.x] = wsum[0] + wsum[1] + wsum[2] + wsum[3];
}

// ---------------- scan of 391 block sums (one block) ----------------
__global__ __launch_bounds__(512) void k_bscan(const int* __restrict__ bsum, int* __restrict__ boff,
                                               int* __restrict__ row_start) {
    __shared__ int s[512];
    int tid = threadIdx.x;
    int v = (tid < NB) ? bsum[tid] : 0;
    s[tid] = v;
    __syncthreads();
    for (int d = 1; d < 512; d <<= 1) {
        int t = (tid >= d) ? s[tid - d] : 0;
        __syncthreads();
        s[tid] += t;
        __syncthreads();
    }
    if (tid < NB) boff[tid] = s[tid] - v;   // exclusive
    if (tid == 0) row_start[NN] = EE;
}

// ---------------- final scan: row_start + deg_inv ----------------
__global__ __launch_bounds__(256) void k_scan2(const int* __restrict__ deg, const int* __restrict__ boff,
                                               int* __restrict__ row_start, float* __restrict__ deg_inv) {
    int tid = threadIdx.x, lane = tid & 63, wid = tid >> 6;
    int i = blockIdx.x * 256 + tid;
    int v = (i < NN) ? deg[i] : 0;
    int inc = v;
#pragma unroll
    for (int d = 1; d < 64; d <<= 1) {
        int t = __shfl_up(inc, d, 64);
        if (lane >= d) inc += t;
    }
    __shared__ int wsum[4];
    if (lane == 63) wsum[wid] = inc;
    __syncthreads();
    if (tid == 0) {
        int s = 0;
#pragma unroll
        for (int j = 0; j < 4; ++j) { int t = wsum[j]; wsum[j] = s; s += t; }
    }
    __syncthreads();
    if (i < NN) {
        row_start[i] = boff[blockIdx.x] + wsum[wid] + (inc - v);
        deg_inv[i] = (v > 0) ? 1.0f / (float)v : 0.0f;
    }
}

// ---------------- fp32 -> bf16 row convert (x: N x 40) ----------------
__global__ __launch_bounds__(256) void k_cvt(const float* __restrict__ x, unsigned short* __restrict__ xb) {
    int i = blockIdx.x * 256 + threadIdx.x;            // groups of 8 elems
    if (i >= NN * 40 / 8) return;
    const float4* p = (const float4*)(x + (size_t)i * 8);
    float4 a = p[0], b = p[1];
    short8 v;
    v[0] = (short)f2bf(a.x); v[1] = (short)f2bf(a.y); v[2] = (short)f2bf(a.z); v[3] = (short)f2bf(a.w);
    v[4] = (short)f2bf(b.x); v[5] = (short)f2bf(b.y); v[6] = (short)f2bf(b.z); v[7] = (short)f2bf(b.w);
    *(short8*)(xb + (size_t)i * 8) = v;
}

// ---------------- bf16 mean-aggregate into concat A = [mean(FinP) | root(FinP)] ----------------
template<int Fin, int FinP>
__global__ __launch_bounds__(256) void k_meanb(const unsigned short* __restrict__ xin,
                                               const int* __restrict__ row_start,
                                               const int* __restrict__ csr_src,
                                               const float* __restrict__ deg_inv,
                                               unsigned short* __restrict__ Acat) {
    constexpr int CH = Fin / 8;     // data chunks (5 or 8)
    constexpr int PCH = FinP / 8;   // padded chunks (6 or 8)
    constexpr int K2 = 2 * FinP;
    int gid = blockIdx.x * 256 + threadIdx.x;
    int node = gid >> 3;
    int c = gid & 7;
    if (node >= NN) return;
    float acc[8] = {0, 0, 0, 0, 0, 0, 0, 0};
    if (c < CH) {
        const unsigned short* xq = xin + c * 8;
        int rs = row_start[node], re = row_start[node + 1];
        int k = rs;
        for (; k + 4 <= re; k += 4) {
            int s0 = csr_src[k], s1 = csr_src[k + 1], s2 = csr_src[k + 2], s3 = csr_src[k + 3];
            short8 v0 = *(const short8*)(xq + (size_t)s0 * Fin);
            short8 v1 = *(const short8*)(xq + (size_t)s1 * Fin);
            short8 v2 = *(const short8*)(xq + (size_t)s2 * Fin);
            short8 v3 = *(const short8*)(xq + (size_t)s3 * Fin);
#pragma unroll
            for (int j = 0; j < 8; ++j)
                acc[j] += (bf2f((unsigned short)v0[j]) + bf2f((unsigned short)v1[j]))
                        + (bf2f((unsigned short)v2[j]) + bf2f((unsigned short)v3[j]));
        }
        for (; k < re; ++k) {
            short8 v0 = *(const short8*)(xq + (size_t)csr_src[k] * Fin);
#pragma unroll
            for (int j = 0; j < 8; ++j) acc[j] += bf2f((unsigned short)v0[j]);
        }
        float di = deg_inv[node];
#pragma unroll
        for (int j = 0; j < 8; ++j) acc[j] *= di;
    }
    if (c < PCH) {
        short8 m;
#pragma unroll
        for (int j = 0; j < 8; ++j) m[j] = (c < CH) ? (short)f2bf(acc[j]) : (short)0;
        *(short8*)(Acat + (size_t)node * K2 + c * 8) = m;
        short8 rv;
        if (c < CH) {
            rv = *(const short8*)(xin + (size_t)node * Fin + c * 8);
        } else {
#pragma unroll
            for (int j = 0; j < 8; ++j) rv[j] = 0;
        }
        *(short8*)(Acat + (size_t)node * K2 + FinP + c * 8) = rv;
    }
}

// ---------------- MFMA GEMM: out = relu?(A @ [Wl;Wr]^T + b), A = N x 2FinP bf16 ----------------
template<int Fin, int FinP, int Fout, bool RELU>
__global__ __launch_bounds__(256) void k_gemm(const unsigned short* __restrict__ A,
                                              const float* __restrict__ Wl,
                                              const float* __restrict__ bias,
                                              const float* __restrict__ Wr,
                                              unsigned short* __restrict__ out) {
    constexpr int K = 2 * FinP;
    constexpr int KS = K / 32;
    constexpr int TILES = Fout / 16;
    __shared__ short sB[TILES * KS * 64 * 8];
    const int lane = threadIdx.x & 63;
    for (int idx = threadIdx.x; idx < TILES * KS * 64; idx += 256) {
        int l = idx & 63;
        int ks = (idx >> 6) % KS;
        int t = idx / (64 * KS);
        int o = t * 16 + (l & 15);
        int kbase = ks * 32 + (l >> 4) * 8;
        short8 v;
#pragma unroll
        for (int j = 0; j < 8; ++j) {
            int k = kbase + j;
            float w;
            if (k < FinP) w = (k < Fin) ? Wl[(size_t)o * Fin + k] : 0.f;
            else { int k2 = k - FinP; w = (k2 < Fin) ? Wr[(size_t)o * Fin + k2] : 0.f; }
            v[j] = (short)f2bf(w);
        }
        *(short8*)&sB[idx * 8] = v;
    }
    __syncthreads();
    float bias_t[TILES];
#pragma unroll
    for (int t = 0; t < TILES; ++t) bias_t[t] = bias[t * 16 + (lane & 15)];

    const int wave = blockIdx.x * 4 + (threadIdx.x >> 6);
    const int nchunks = NN / 32;                        // 3125
    for (int ci = wave; ci < nchunks; ci += gridDim.x * 4) {
        int nbase = ci * 32;
        const unsigned short* a0 = A + (size_t)(nbase + (lane & 15)) * K + (lane >> 4) * 8;
        short8 af[2][KS];
#pragma unroll
        for (int ks = 0; ks < KS; ++ks) {
            af[0][ks] = *(const short8*)(a0 + ks * 32);
            af[1][ks] = *(const short8*)(a0 + 16 * K + ks * 32);
        }
        f32x4 acc[2][TILES];
#pragma unroll
        for (int m = 0; m < 2; ++m)
#pragma unroll
            for (int t = 0; t < TILES; ++t) acc[m][t] = (f32x4){0.f, 0.f, 0.f, 0.f};
#pragma unroll
        for (int t = 0; t < TILES; ++t)
#pragma unroll
            for (int ks = 0; ks < KS; ++ks) {
                short8 bf = *(const short8*)&sB[((t * KS + ks) * 64 + lane) * 8];
                acc[0][t] = __builtin_amdgcn_mfma_f32_16x16x32_bf16(af[0][ks], bf, acc[0][t], 0, 0, 0);
                acc[1][t] = __builtin_amdgcn_mfma_f32_16x16x32_bf16(af[1][ks], bf, acc[1][t], 0, 0, 0);
            }
#pragma unroll
        for (int m = 0; m < 2; ++m) {
            int nrow = nbase + m * 16 + (lane >> 4) * 4;
#pragma unroll
            for (int t = 0; t < TILES; ++t) {
                int col = t * 16 + (lane & 15);
#pragma unroll
                for (int r = 0; r < 4; ++r) {
                    float v = acc[m][t][r] + bias_t[t];
                    if (RELU) v = fmaxf(v, 0.f);
                    out[(size_t)(nrow + r) * Fout + col] = f2bf(v);
                }
            }
        }
    }
}

// ---------------- layer 3 transforms: z = h2@W4l.T, r = h2@W4r.T (h2 bf16) ----------------
__global__ __launch_bounds__(256) void k_zr(const unsigned short* __restrict__ h2,
                                            const float* __restrict__ W4l, const float* __restrict__ W4r,
                                            float* __restrict__ z, float* __restrict__ r) {
    int node = (blockIdx.x * 256 + threadIdx.x) >> 6;
    int lane = threadIdx.x & 63;
    if (node >= NN) return;
    float h0 = bf2f(h2[(size_t)node * 128 + lane]);
    float h1v = bf2f(h2[(size_t)node * 128 + 64 + lane]);
    float zc0 = h0 * W4l[0 * 128 + lane] + h1v * W4l[0 * 128 + 64 + lane];
    float zc1 = h0 * W4l[1 * 128 + lane] + h1v * W4l[1 * 128 + 64 + lane];
    float zc2 = h0 * W4l[2 * 128 + lane] + h1v * W4l[2 * 128 + 64 + lane];
    float rc0 = h0 * W4r[0 * 128 + lane] + h1v * W4r[0 * 128 + 64 + lane];
    float rc1 = h0 * W4r[1 * 128 + lane] + h1v * W4r[1 * 128 + 64 + lane];
    float rc2 = h0 * W4r[2 * 128 + lane] + h1v * W4r[2 * 128 + 64 + lane];
#pragma unroll
    for (int d = 32; d; d >>= 1) {
        zc0 += __shfl_down(zc0, d, 64); zc1 += __shfl_down(zc1, d, 64); zc2 += __shfl_down(zc2, d, 64);
        rc0 += __shfl_down(rc0, d, 64); rc1 += __shfl_down(rc1, d, 64); rc2 += __shfl_down(rc2, d, 64);
    }
    if (lane == 0) {
        *(float4*)&z[(size_t)node * 4] = make_float4(zc0, zc1, zc2, 0.f);
        *(float4*)&r[(size_t)node * 4] = make_float4(rc0, rc1, rc2, 0.f);
    }
}

// ---------------- final: out = mean(z)[n] + r[n] + b4 ----------------
__global__ __launch_bounds__(256) void k_final(const float* __restrict__ z, const float* __restrict__ r,
                                               const float* __restrict__ b4,
                                               const int* __restrict__ row_start, const int* __restrict__ csr_src,
                                               const float* __restrict__ deg_inv, float* __restrict__ out) {
    int n = blockIdx.x * 256 + threadIdx.x;
    if (n >= NN) return;
    int rs = row_start[n], re = row_start[n + 1];
    float a0 = 0, a1 = 0, a2 = 0, b0 = 0, b1 = 0, b2 = 0;
    int k = rs;
    for (; k + 4 <= re; k += 4) {
        int s0 = csr_src[k], s1 = csr_src[k + 1], s2 = csr_src[k + 2], s3 = csr_src[k + 3];
        float4 z0 = *(const float4*)&z[4 * (size_t)s0];
        float4 z1 = *(const float4*)&z[4 * (size_t)s1];
        float4 z2 = *(const float4*)&z[4 * (size_t)s2];
        float4 z3 = *(const float4*)&z[4 * (size_t)s3];
        a0 += z0.x; a1 += z0.y; a2 += z0.z;
        b0 += z1.x; b1 += z1.y; b2 += z1.z;
        a0 += z2.x; a1 += z2.y; a2 += z2.z;
        b0 += z3.x; b1 += z3.y; b2 += z3.z;
    }
    for (; k < re; ++k) {
        float4 z0 = *(const float4*)&z[4 * (size_t)csr_src[k]];
        a0 += z0.x; a1 += z0.y; a2 += z0.z;
    }
    float di = deg_inv[n];
    float4 rn = *(const float4*)&r[4 * (size_t)n];
    out[(size_t)n * 3 + 0] = (a0 + b0) * di + rn.x + b4[0];
    out[(size_t)n * 3 + 1] = (a1 + b1) * di + rn.y + b4[1];
    out[(size_t)n * 3 + 2] = (a2 + b2) * di + rn.z + b4[2];
}

extern "C" void kernel_launch(void* const* d_in, const int* in_sizes, int n_in,
                              void* d_out, int out_size, void* d_ws, size_t ws_size,
                              hipStream_t stream) {
    const float* x   = (const float*)d_in[0];
    const int*   ei  = (const int*)d_in[1];
    const float* W1l = (const float*)d_in[2];
    const float* b1  = (const float*)d_in[3];
    const float* W1r = (const float*)d_in[4];
    const float* W2l = (const float*)d_in[5];
    const float* b2  = (const float*)d_in[6];
    const float* W2r = (const float*)d_in[7];
    const float* W4l = (const float*)d_in[8];
    const float* b4  = (const float*)d_in[9];
    const float* W4r = (const float*)d_in[10];
    float* out = (float*)d_out;

    char* ws = (char*)d_ws;
    size_t off = 0;
    auto alloc = [&](size_t bytes) -> void* {
        void* p = ws + off;
        off = (off + bytes + 255) & ~(size_t)255;
        return p;
    };
    int*   deg       = (int*)alloc((size_t)NN * 4);
    int*   row_start = (int*)alloc(((size_t)NN + 1) * 4);
    int*   cursor    = (int*)alloc((size_t)NN * 4);
    int*   csr_src   = (int*)alloc((size_t)EE * 4);
    float* deg_inv   = (float*)alloc((size_t)NN * 4);
    int*   bsum      = (int*)alloc((size_t)NB * 4);
    int*   boff      = (int*)alloc((size_t)NB * 4);
    int*   pcur      = (int*)alloc((size_t)NBUCKET * 4);
    unsigned short* xb    = (unsigned short*)alloc((size_t)NN * 40 * 2);
    unsigned short* A1cat = (unsigned short*)alloc((size_t)NN * 96 * 2);
    unsigned short* h1    = (unsigned short*)alloc((size_t)NN * 64 * 2);
    unsigned short* A2cat = (unsigned short*)alloc((size_t)NN * 128 * 2);  // 25.6 MB
    unsigned short* h2    = (unsigned short*)alloc((size_t)NN * 128 * 2);
    float* zbuf = (float*)alloc((size_t)NN * 4 * 4);
    float* rbuf = (float*)alloc((size_t)NN * 4 * 4);
    // pairs (16.8 MB) aliases A2cat: dead before A2cat first written (layer-2 k_meanb)
    int2* pairs = (int2*)A2cat;

    const int* e_src = ei;
    const int* e_dst = ei + EE;

    hipMemsetAsync(deg, 0, (size_t)NN * 4, stream);
    hipMemsetAsync(cursor, 0, (size_t)NN * 4, stream);
    hipMemsetAsync(pcur, 0, (size_t)NBUCKET * 4, stream);

    // phase 1: bucket + degree (each edge read/processed exactly once)
    k_bucket<<<BUCKET_BLOCKS, 256, 0, stream>>>(e_src, e_dst, deg, pcur, pairs);
    k_cvt<<<((NN * 40 / 8) + 255) / 256, 256, 0, stream>>>(x, xb);
    k_bsum<<<NB, 256, 0, stream>>>(deg, bsum);
    k_bscan<<<1, 512, 0, stream>>>(bsum, boff, row_start);
    k_scan2<<<NB, 256, 0, stream>>>(deg, boff, row_start, deg_inv);
    // phase 2: XCD-local scatter into CSR
    k_scatter<<<1024, 256, 0, stream>>>(pairs, pcur, row_start, cursor, csr_src);

    const int mean_blocks = ((size_t)NN * 8 + 255) / 256;   // 3125
    const int gemm_blocks = 782;

    // layer 1: 40 -> 64  (K = 2*48 = 96)
    k_meanb<40, 48><<<mean_blocks, 256, 0, stream>>>(xb, row_start, csr_src, deg_inv, A1cat);
    k_gemm<40, 48, 64, true><<<gemm_blocks, 256, 0, stream>>>(A1cat, W1l, b1, W1r, h1);

    // layer 2: 64 -> 128  (K = 128)
    k_meanb<64, 64><<<mean_blocks, 256, 0, stream>>>(h1, row_start, csr_src, deg_inv, A2cat);
    k_gemm<64, 64, 128, true><<<gemm_blocks, 256, 0, stream>>>(A2cat, W2l, b2, W2r, h2);

    // layer 3: 128 -> 3, transform-before-gather
    k_zr<<<((size_t)NN * 64 + 255) / 256, 256, 0, stream>>>(h2, W4l, W4r, zbuf, rbuf);
    k_final<<<(NN + 255) / 256, 256, 0, stream>>>(zbuf, rbuf, b4, row_start, csr_src, deg_inv, out);
}

// Round 11
// 385.843 us; speedup vs baseline: 2.3292x; 2.3292x over previous
//
#include <hip/hip_runtime.h>
#include <hip/hip_bf16.h>

// GraphSAGE 3-layer: 40 -> 64 -> 128 -> 3, mean aggregation over fixed edges.
// R11: R10's k_bucket died of per-edge global atomic contention (1.6M RMWs
// on 512 counters -> 585us serialized). Now block-local reservation: LDS
// count (64 buckets) -> ONE global atomicAdd per bucket per block (50K total)
// -> contiguous span write (~256B/bucket/block, full-line). k_scatter proven
// cheap, unchanged. Fallback if this fails: revert to R6 single-pass fill.

static constexpr int NN = 100000;
static constexpr int EE = 1600000;
static constexpr int NB = (NN + 255) / 256;   // 391 scan blocks
static constexpr int NRANGE = 64;
static constexpr int RSIZE = (NN + NRANGE - 1) / NRANGE;   // 1563
static constexpr int NBUCKET = 8 * NRANGE;                 // 512
static constexpr int CAP = 4096;     // per-bucket capacity (mean 3125, ~17 sigma)
static constexpr int BCHUNK = 2048;  // edges per block (8 per thread)
static constexpr int BUCKET_BLOCKS = (EE + BCHUNK - 1) / BCHUNK;  // 782

typedef __attribute__((ext_vector_type(8))) short short8;
typedef __attribute__((ext_vector_type(4))) float f32x4;

__device__ __forceinline__ float bf2f(unsigned short u) {
    union { unsigned int i; float f; } c; c.i = ((unsigned int)u) << 16; return c.f;
}
__device__ __forceinline__ unsigned short f2bf(float f) {
    union { float f; unsigned int i; } c; c.f = f;
    unsigned int x = c.i;
    return (unsigned short)((x + 0x7fffu + ((x >> 16) & 1u)) >> 16);   // RNE
}

// ---------------- phase 1: bucket edges by (xcd, dst-range), block-local reservation ----------------
__global__ __launch_bounds__(256) void k_bucket(const int* __restrict__ src, const int* __restrict__ dst,
                                                int* __restrict__ deg, int* __restrict__ pcur,
                                                int2* __restrict__ pairs) {
    __shared__ int cnt[NRANGE];
    __shared__ int base[NRANGE];
    const int part = blockIdx.x & 7;            // this block's XCD tag (round-robin)
    const int e0 = blockIdx.x * BCHUNK;
    const int tid = threadIdx.x;
    if (tid < NRANGE) cnt[tid] = 0;
    __syncthreads();
    int r_[8], lp_[8];
    int2 sd_[8];
#pragma unroll
    for (int j = 0; j < 8; ++j) {
        int e = e0 + j * 256 + tid;
        r_[j] = -1;
        if (e < EE) {
            int d = dst[e];
            int s = src[e];
            atomicAdd(&deg[d], 1);
            int r = d / RSIZE;                  // const-divide -> magic mul
            r_[j] = r;
            sd_[j] = make_int2(s, d);
            lp_[j] = atomicAdd(&cnt[r], 1);     // fast LDS atomic
        }
    }
    __syncthreads();
    if (tid < NRANGE) {
        int c = cnt[tid];
        base[tid] = (c > 0) ? atomicAdd(&pcur[(part << 6) | tid], c) : 0;  // 1 global RMW / bucket / block
    }
    __syncthreads();
#pragma unroll
    for (int j = 0; j < 8; ++j) {
        if (r_[j] >= 0) {
            int b = (part << 6) | r_[j];
            int pos = base[r_[j]] + lp_[j];
            if (pos < CAP) pairs[(size_t)b * CAP + pos] = sd_[j];
        }
    }
}

// ---------------- phase 2: scatter buckets into CSR (XCD-local csr window) ----------------
__global__ __launch_bounds__(256) void k_scatter(const int2* __restrict__ pairs, const int* __restrict__ pcur,
                                                 const int* __restrict__ row_start, int* __restrict__ cursor,
                                                 int* __restrict__ csr_src) {
    const int r = blockIdx.x & 63;              // dst range; XCD = r%8 = blockIdx%8
    const int j = blockIdx.x >> 6;              // 0..15 sub-chunk
    for (int p = 0; p < 8; ++p) {
        int b = (p << 6) | r;
        int len = pcur[b];
        if (len > CAP) len = CAP;
        int i0 = (len * j) >> 4;
        int i1 = (len * (j + 1)) >> 4;
        const int2* base = pairs + (size_t)b * CAP;
        for (int i = i0 + threadIdx.x; i < i1; i += 256) {
            int2 e = base[i];
            int pos = atomicAdd(&cursor[e.y], 1);
            csr_src[row_start[e.y] + pos] = e.x;
        }
    }
}

// ---------------- hierarchical scan: block sums ----------------
__global__ __launch_bounds__(256) void k_bsum(const int* __restrict__ deg, int* __restrict__ bsum) {
    int i = blockIdx.x * 256 + threadIdx.x;
    int v = (i < NN) ? deg[i] : 0;
    int lane = threadIdx.x & 63, wid = threadIdx.x >> 6;
#pragma unroll
    for (int d = 32; d; d >>= 1) v += __shfl_down(v, d, 64);
    __shared__ int wsum[4];
    if (lane == 0) wsum[wid] = v;
    __syncthreads();
    if (threadIdx.x == 0) bsum[blockIdx.x] = wsum[0] + wsum[1] + wsum[2] + wsum[3];
}

// ---------------- scan of 391 block sums (one block) ----------------
__global__ __launch_bounds__(512) void k_bscan(const int* __restrict__ bsum, int* __restrict__ boff,
                                               int* __restrict__ row_start) {
    __shared__ int s[512];
    int tid = threadIdx.x;
    int v = (tid < NB) ? bsum[tid] : 0;
    s[tid] = v;
    __syncthreads();
    for (int d = 1; d < 512; d <<= 1) {
        int t = (tid >= d) ? s[tid - d] : 0;
        __syncthreads();
        s[tid] += t;
        __syncthreads();
    }
    if (tid < NB) boff[tid] = s[tid] - v;   // exclusive
    if (tid == 0) row_start[NN] = EE;
}

// ---------------- final scan: row_start + deg_inv ----------------
__global__ __launch_bounds__(256) void k_scan2(const int* __restrict__ deg, const int* __restrict__ boff,
                                               int* __restrict__ row_start, float* __restrict__ deg_inv) {
    int tid = threadIdx.x, lane = tid & 63, wid = tid >> 6;
    int i = blockIdx.x * 256 + tid;
    int v = (i < NN) ? deg[i] : 0;
    int inc = v;
#pragma unroll
    for (int d = 1; d < 64; d <<= 1) {
        int t = __shfl_up(inc, d, 64);
        if (lane >= d) inc += t;
    }
    __shared__ int wsum[4];
    if (lane == 63) wsum[wid] = inc;
    __syncthreads();
    if (tid == 0) {
        int s = 0;
#pragma unroll
        for (int j = 0; j < 4; ++j) { int t = wsum[j]; wsum[j] = s; s += t; }
    }
    __syncthreads();
    if (i < NN) {
        row_start[i] = boff[blockIdx.x] + wsum[wid] + (inc - v);
        deg_inv[i] = (v > 0) ? 1.0f / (float)v : 0.0f;
    }
}

// ---------------- fp32 -> bf16 row convert (x: N x 40) ----------------
__global__ __launch_bounds__(256) void k_cvt(const float* __restrict__ x, unsigned short* __restrict__ xb) {
    int i = blockIdx.x * 256 + threadIdx.x;            // groups of 8 elems
    if (i >= NN * 40 / 8) return;
    const float4* p = (const float4*)(x + (size_t)i * 8);
    float4 a = p[0], b = p[1];
    short8 v;
    v[0] = (short)f2bf(a.x); v[1] = (short)f2bf(a.y); v[2] = (short)f2bf(a.z); v[3] = (short)f2bf(a.w);
    v[4] = (short)f2bf(b.x); v[5] = (short)f2bf(b.y); v[6] = (short)f2bf(b.z); v[7] = (short)f2bf(b.w);
    *(short8*)(xb + (size_t)i * 8) = v;
}

// ---------------- bf16 mean-aggregate into concat A = [mean(FinP) | root(FinP)] ----------------
template<int Fin, int FinP>
__global__ __launch_bounds__(256) void k_meanb(const unsigned short* __restrict__ xin,
                                               const int* __restrict__ row_start,
                                               const int* __restrict__ csr_src,
                                               const float* __restrict__ deg_inv,
                                               unsigned short* __restrict__ Acat) {
    constexpr int CH = Fin / 8;     // data chunks (5 or 8)
    constexpr int PCH = FinP / 8;   // padded chunks (6 or 8)
    constexpr int K2 = 2 * FinP;
    int gid = blockIdx.x * 256 + threadIdx.x;
    int node = gid >> 3;
    int c = gid & 7;
    if (node >= NN) return;
    float acc[8] = {0, 0, 0, 0, 0, 0, 0, 0};
    if (c < CH) {
        const unsigned short* xq = xin + c * 8;
        int rs = row_start[node], re = row_start[node + 1];
        int k = rs;
        for (; k + 4 <= re; k += 4) {
            int s0 = csr_src[k], s1 = csr_src[k + 1], s2 = csr_src[k + 2], s3 = csr_src[k + 3];
            short8 v0 = *(const short8*)(xq + (size_t)s0 * Fin);
            short8 v1 = *(const short8*)(xq + (size_t)s1 * Fin);
            short8 v2 = *(const short8*)(xq + (size_t)s2 * Fin);
            short8 v3 = *(const short8*)(xq + (size_t)s3 * Fin);
#pragma unroll
            for (int j = 0; j < 8; ++j)
                acc[j] += (bf2f((unsigned short)v0[j]) + bf2f((unsigned short)v1[j]))
                        + (bf2f((unsigned short)v2[j]) + bf2f((unsigned short)v3[j]));
        }
        for (; k < re; ++k) {
            short8 v0 = *(const short8*)(xq + (size_t)csr_src[k] * Fin);
#pragma unroll
            for (int j = 0; j < 8; ++j) acc[j] += bf2f((unsigned short)v0[j]);
        }
        float di = deg_inv[node];
#pragma unroll
        for (int j = 0; j < 8; ++j) acc[j] *= di;
    }
    if (c < PCH) {
        short8 m;
#pragma unroll
        for (int j = 0; j < 8; ++j) m[j] = (c < CH) ? (short)f2bf(acc[j]) : (short)0;
        *(short8*)(Acat + (size_t)node * K2 + c * 8) = m;
        short8 rv;
        if (c < CH) {
            rv = *(const short8*)(xin + (size_t)node * Fin + c * 8);
        } else {
#pragma unroll
            for (int j = 0; j < 8; ++j) rv[j] = 0;
        }
        *(short8*)(Acat + (size_t)node * K2 + FinP + c * 8) = rv;
    }
}

// ---------------- MFMA GEMM: out = relu?(A @ [Wl;Wr]^T + b), A = N x 2FinP bf16 ----------------
template<int Fin, int FinP, int Fout, bool RELU>
__global__ __launch_bounds__(256) void k_gemm(const unsigned short* __restrict__ A,
                                              const float* __restrict__ Wl,
                                              const float* __restrict__ bias,
                                              const float* __restrict__ Wr,
                                              unsigned short* __restrict__ out) {
    constexpr int K = 2 * FinP;
    constexpr int KS = K / 32;
    constexpr int TILES = Fout / 16;
    __shared__ short sB[TILES * KS * 64 * 8];
    const int lane = threadIdx.x & 63;
    for (int idx = threadIdx.x; idx < TILES * KS * 64; idx += 256) {
        int l = idx & 63;
        int ks = (idx >> 6) % KS;
        int t = idx / (64 * KS);
        int o = t * 16 + (l & 15);
        int kbase = ks * 32 + (l >> 4) * 8;
        short8 v;
#pragma unroll
        for (int j = 0; j < 8; ++j) {
            int k = kbase + j;
            float w;
            if (k < FinP) w = (k < Fin) ? Wl[(size_t)o * Fin + k] : 0.f;
            else { int k2 = k - FinP; w = (k2 < Fin) ? Wr[(size_t)o * Fin + k2] : 0.f; }
            v[j] = (short)f2bf(w);
        }
        *(short8*)&sB[idx * 8] = v;
    }
    __syncthreads();
    float bias_t[TILES];
#pragma unroll
    for (int t = 0; t < TILES; ++t) bias_t[t] = bias[t * 16 + (lane & 15)];

    const int wave = blockIdx.x * 4 + (threadIdx.x >> 6);
    const int nchunks = NN / 32;                        // 3125
    for (int ci = wave; ci < nchunks; ci += gridDim.x * 4) {
        int nbase = ci * 32;
        const unsigned short* a0 = A + (size_t)(nbase + (lane & 15)) * K + (lane >> 4) * 8;
        short8 af[2][KS];
#pragma unroll
        for (int ks = 0; ks < KS; ++ks) {
            af[0][ks] = *(const short8*)(a0 + ks * 32);
            af[1][ks] = *(const short8*)(a0 + 16 * K + ks * 32);
        }
        f32x4 acc[2][TILES];
#pragma unroll
        for (int m = 0; m < 2; ++m)
#pragma unroll
            for (int t = 0; t < TILES; ++t) acc[m][t] = (f32x4){0.f, 0.f, 0.f, 0.f};
#pragma unroll
        for (int t = 0; t < TILES; ++t)
#pragma unroll
            for (int ks = 0; ks < KS; ++ks) {
                short8 bf = *(const short8*)&sB[((t * KS + ks) * 64 + lane) * 8];
                acc[0][t] = __builtin_amdgcn_mfma_f32_16x16x32_bf16(af[0][ks], bf, acc[0][t], 0, 0, 0);
                acc[1][t] = __builtin_amdgcn_mfma_f32_16x16x32_bf16(af[1][ks], bf, acc[1][t], 0, 0, 0);
            }
#pragma unroll
        for (int m = 0; m < 2; ++m) {
            int nrow = nbase + m * 16 + (lane >> 4) * 4;
#pragma unroll
            for (int t = 0; t < TILES; ++t) {
                int col = t * 16 + (lane & 15);
#pragma unroll
                for (int r = 0; r < 4; ++r) {
                    float v = acc[m][t][r] + bias_t[t];
                    if (RELU) v = fmaxf(v, 0.f);
                    out[(size_t)(nrow + r) * Fout + col] = f2bf(v);
                }
            }
        }
    }
}

// ---------------- layer 3 transforms: z = h2@W4l.T, r = h2@W4r.T (h2 bf16) ----------------
__global__ __launch_bounds__(256) void k_zr(const unsigned short* __restrict__ h2,
                                            const float* __restrict__ W4l, const float* __restrict__ W4r,
                                            float* __restrict__ z, float* __restrict__ r) {
    int node = (blockIdx.x * 256 + threadIdx.x) >> 6;
    int lane = threadIdx.x & 63;
    if (node >= NN) return;
    float h0 = bf2f(h2[(size_t)node * 128 + lane]);
    float h1v = bf2f(h2[(size_t)node * 128 + 64 + lane]);
    float zc0 = h0 * W4l[0 * 128 + lane] + h1v * W4l[0 * 128 + 64 + lane];
    float zc1 = h0 * W4l[1 * 128 + lane] + h1v * W4l[1 * 128 + 64 + lane];
    float zc2 = h0 * W4l[2 * 128 + lane] + h1v * W4l[2 * 128 + 64 + lane];
    float rc0 = h0 * W4r[0 * 128 + lane] + h1v * W4r[0 * 128 + 64 + lane];
    float rc1 = h0 * W4r[1 * 128 + lane] + h1v * W4r[1 * 128 + 64 + lane];
    float rc2 = h0 * W4r[2 * 128 + lane] + h1v * W4r[2 * 128 + 64 + lane];
#pragma unroll
    for (int d = 32; d; d >>= 1) {
        zc0 += __shfl_down(zc0, d, 64); zc1 += __shfl_down(zc1, d, 64); zc2 += __shfl_down(zc2, d, 64);
        rc0 += __shfl_down(rc0, d, 64); rc1 += __shfl_down(rc1, d, 64); rc2 += __shfl_down(rc2, d, 64);
    }
    if (lane == 0) {
        *(float4*)&z[(size_t)node * 4] = make_float4(zc0, zc1, zc2, 0.f);
        *(float4*)&r[(size_t)node * 4] = make_float4(rc0, rc1, rc2, 0.f);
    }
}

// ---------------- final: out = mean(z)[n] + r[n] + b4 ----------------
__global__ __launch_bounds__(256) void k_final(const float* __restrict__ z, const float* __restrict__ r,
                                               const float* __restrict__ b4,
                                               const int* __restrict__ row_start, const int* __restrict__ csr_src,
                                               const float* __restrict__ deg_inv, float* __restrict__ out) {
    int n = blockIdx.x * 256 + threadIdx.x;
    if (n >= NN) return;
    int rs = row_start[n], re = row_start[n + 1];
    float a0 = 0, a1 = 0, a2 = 0, b0 = 0, b1 = 0, b2 = 0;
    int k = rs;
    for (; k + 4 <= re; k += 4) {
        int s0 = csr_src[k], s1 = csr_src[k + 1], s2 = csr_src[k + 2], s3 = csr_src[k + 3];
        float4 z0 = *(const float4*)&z[4 * (size_t)s0];
        float4 z1 = *(const float4*)&z[4 * (size_t)s1];
        float4 z2 = *(const float4*)&z[4 * (size_t)s2];
        float4 z3 = *(const float4*)&z[4 * (size_t)s3];
        a0 += z0.x; a1 += z0.y; a2 += z0.z;
        b0 += z1.x; b1 += z1.y; b2 += z1.z;
        a0 += z2.x; a1 += z2.y; a2 += z2.z;
        b0 += z3.x; b1 += z3.y; b2 += z3.z;
    }
    for (; k < re; ++k) {
        float4 z0 = *(const float4*)&z[4 * (size_t)csr_src[k]];
        a0 += z0.x; a1 += z0.y; a2 += z0.z;
    }
    float di = deg_inv[n];
    float4 rn = *(const float4*)&r[4 * (size_t)n];
    out[(size_t)n * 3 + 0] = (a0 + b0) * di + rn.x + b4[0];
    out[(size_t)n * 3 + 1] = (a1 + b1) * di + rn.y + b4[1];
    out[(size_t)n * 3 + 2] = (a2 + b2) * di + rn.z + b4[2];
}

extern "C" void kernel_launch(void* const* d_in, const int* in_sizes, int n_in,
                              void* d_out, int out_size, void* d_ws, size_t ws_size,
                              hipStream_t stream) {
    const float* x   = (const float*)d_in[0];
    const int*   ei  = (const int*)d_in[1];
    const float* W1l = (const float*)d_in[2];
    const float* b1  = (const float*)d_in[3];
    const float* W1r = (const float*)d_in[4];
    const float* W2l = (const float*)d_in[5];
    const float* b2  = (const float*)d_in[6];
    const float* W2r = (const float*)d_in[7];
    const float* W4l = (const float*)d_in[8];
    const float* b4  = (const float*)d_in[9];
    const float* W4r = (const float*)d_in[10];
    float* out = (float*)d_out;

    char* ws = (char*)d_ws;
    size_t off = 0;
    auto alloc = [&](size_t bytes) -> void* {
        void* p = ws + off;
        off = (off + bytes + 255) & ~(size_t)255;
        return p;
    };
    int*   deg       = (int*)alloc((size_t)NN * 4);
    int*   row_start = (int*)alloc(((size_t)NN + 1) * 4);
    int*   cursor    = (int*)alloc((size_t)NN * 4);
    int*   csr_src   = (int*)alloc((size_t)EE * 4);
    float* deg_inv   = (float*)alloc((size_t)NN * 4);
    int*   bsum      = (int*)alloc((size_t)NB * 4);
    int*   boff      = (int*)alloc((size_t)NB * 4);
    int*   pcur      = (int*)alloc((size_t)NBUCKET * 4);
    unsigned short* xb    = (unsigned short*)alloc((size_t)NN * 40 * 2);
    unsigned short* A1cat = (unsigned short*)alloc((size_t)NN * 96 * 2);
    unsigned short* h1    = (unsigned short*)alloc((size_t)NN * 64 * 2);
    unsigned short* A2cat = (unsigned short*)alloc((size_t)NN * 128 * 2);  // 25.6 MB
    unsigned short* h2    = (unsigned short*)alloc((size_t)NN * 128 * 2);
    float* zbuf = (float*)alloc((size_t)NN * 4 * 4);
    float* rbuf = (float*)alloc((size_t)NN * 4 * 4);
    // pairs (16.8 MB) aliases A2cat: dead before A2cat first written (layer-2 k_meanb)
    int2* pairs = (int2*)A2cat;

    const int* e_src = ei;
    const int* e_dst = ei + EE;

    hipMemsetAsync(deg, 0, (size_t)NN * 4, stream);
    hipMemsetAsync(cursor, 0, (size_t)NN * 4, stream);
    hipMemsetAsync(pcur, 0, (size_t)NBUCKET * 4, stream);

    // phase 1: bucket + degree (each edge read once; block-local reservation)
    k_bucket<<<BUCKET_BLOCKS, 256, 0, stream>>>(e_src, e_dst, deg, pcur, pairs);
    k_cvt<<<((NN * 40 / 8) + 255) / 256, 256, 0, stream>>>(x, xb);
    k_bsum<<<NB, 256, 0, stream>>>(deg, bsum);
    k_bscan<<<1, 512, 0, stream>>>(bsum, boff, row_start);
    k_scan2<<<NB, 256, 0, stream>>>(deg, boff, row_start, deg_inv);
    // phase 2: XCD-local scatter into CSR
    k_scatter<<<1024, 256, 0, stream>>>(pairs, pcur, row_start, cursor, csr_src);

    const int mean_blocks = ((size_t)NN * 8 + 255) / 256;   // 3125
    const int gemm_blocks = 782;

    // layer 1: 40 -> 64  (K = 2*48 = 96)
    k_meanb<40, 48><<<mean_blocks, 256, 0, stream>>>(xb, row_start, csr_src, deg_inv, A1cat);
    k_gemm<40, 48, 64, true><<<gemm_blocks, 256, 0, stream>>>(A1cat, W1l, b1, W1r, h1);

    // layer 2: 64 -> 128  (K = 128)
    k_meanb<64, 64><<<mean_blocks, 256, 0, stream>>>(h1, row_start, csr_src, deg_inv, A2cat);
    k_gemm<64, 64, 128, true><<<gemm_blocks, 256, 0, stream>>>(A2cat, W2l, b2, W2r, h2);

    // layer 3: 128 -> 3, transform-before-gather
    k_zr<<<((size_t)NN * 64 + 255) / 256, 256, 0, stream>>>(h2, W4l, W4r, zbuf, rbuf);
    k_final<<<(NN + 255) / 256, 256, 0, stream>>>(zbuf, rbuf, b4, row_start, csr_src, deg_inv, out);
}

// Round 12
// 314.927 us; speedup vs baseline: 2.8537x; 1.2252x over previous
//
#include <hip/hip_runtime.h>
#include <hip/hip_bf16.h>

// GraphSAGE 3-layer: 40 -> 64 -> 128 -> 3, mean aggregation over fixed edges.
// R12: eliminate ALL per-edge global atomics (device-scope atomics serialize
// memory-side past the non-coherent L2s; R11's 62MB WRITE ~= 1.6M deg-atomic
// RMWs). k_bucket: SoA pairs, no deg atomic. k_degr: per-range LDS degree
// count (read pair_d only). k_scatter2: per-range LDS cursors. deg/cursor
// memsets gone. Layer kernels unchanged.

static constexpr int NN = 100000;
static constexpr int EE = 1600000;
static constexpr int NB = (NN + 255) / 256;   // 391 scan blocks
static constexpr int NRANGE = 64;
static constexpr int RSIZE = (NN + NRANGE - 1) / NRANGE;   // 1563
static constexpr int NBUCKET = 8 * NRANGE;                 // 512
static constexpr int CAP = 4096;     // per-bucket capacity (mean ~3130, ~17 sigma)
static constexpr int BCHUNK = 2048;  // edges per block (8 per thread)
static constexpr int BUCKET_BLOCKS = (EE + BCHUNK - 1) / BCHUNK;  // 782

typedef __attribute__((ext_vector_type(8))) short short8;
typedef __attribute__((ext_vector_type(4))) float f32x4;

__device__ __forceinline__ float bf2f(unsigned short u) {
    union { unsigned int i; float f; } c; c.i = ((unsigned int)u) << 16; return c.f;
}
__device__ __forceinline__ unsigned short f2bf(float f) {
    union { float f; unsigned int i; } c; c.f = f;
    unsigned int x = c.i;
    return (unsigned short)((x + 0x7fffu + ((x >> 16) & 1u)) >> 16);   // RNE
}

// ---------------- phase 1: bucket edges by (xcd, dst-range), block-local reservation ----------------
__global__ __launch_bounds__(256) void k_bucket(const int* __restrict__ src, const int* __restrict__ dst,
                                                int* __restrict__ pcur,
                                                int* __restrict__ pair_s, int* __restrict__ pair_d) {
    __shared__ int cnt[NRANGE];
    __shared__ int base[NRANGE];
    const int part = blockIdx.x & 7;            // this block's XCD tag (round-robin)
    const int e0 = blockIdx.x * BCHUNK;
    const int tid = threadIdx.x;
    if (tid < NRANGE) cnt[tid] = 0;
    __syncthreads();
    int r_[8], lp_[8], s_[8], d_[8];
#pragma unroll
    for (int j = 0; j < 8; ++j) {
        int e = e0 + j * 256 + tid;
        r_[j] = -1;
        if (e < EE) {
            int d = dst[e];
            int s = src[e];
            int r = d / RSIZE;                  // const-divide -> magic mul
            r_[j] = r; s_[j] = s; d_[j] = d;
            lp_[j] = atomicAdd(&cnt[r], 1);     // fast LDS atomic
        }
    }
    __syncthreads();
    if (tid < NRANGE) {
        int c = cnt[tid];
        base[tid] = (c > 0) ? atomicAdd(&pcur[(part << 6) | tid], c) : 0;  // 1 global RMW / bucket / block
    }
    __syncthreads();
#pragma unroll
    for (int j = 0; j < 8; ++j) {
        if (r_[j] >= 0) {
            int pos = base[r_[j]] + lp_[j];
            if (pos < CAP) {
                size_t idx = (size_t)((part << 6) | r_[j]) * CAP + pos;
                pair_s[idx] = s_[j];
                pair_d[idx] = d_[j];
            }
        }
    }
}

// ---------------- phase 1.5: per-range degree count in LDS (no global atomics) ----------------
__global__ __launch_bounds__(1024) void k_degr(const int* __restrict__ pair_d, const int* __restrict__ pcur,
                                               int* __restrict__ deg) {
    __shared__ int ldeg[RSIZE];
    const int r = blockIdx.x;                   // 0..63; XCD = r%8
    const int lo = r * RSIZE;
    const int hi = (lo + RSIZE < NN) ? lo + RSIZE : NN;
    for (int t = threadIdx.x; t < RSIZE; t += 1024) ldeg[t] = 0;
    __syncthreads();
    for (int p = 0; p < 8; ++p) {
        int b = (p << 6) | r;
        int len = pcur[b];
        if (len > CAP) len = CAP;
        const int* base = pair_d + (size_t)b * CAP;
        for (int i = threadIdx.x; i < len; i += 1024)
            atomicAdd(&ldeg[base[i] - lo], 1);
    }
    __syncthreads();
    for (int t = threadIdx.x; t < hi - lo; t += 1024)
        deg[lo + t] = ldeg[t];                  // coalesced full-line write, once
}

// ---------------- phase 2: scatter into CSR with per-range LDS cursors ----------------
__global__ __launch_bounds__(1024) void k_scatter2(const int* __restrict__ pair_s, const int* __restrict__ pair_d,
                                                   const int* __restrict__ pcur,
                                                   const int* __restrict__ row_start,
                                                   int* __restrict__ csr_src) {
    __shared__ int lcur[RSIZE];
    const int r = blockIdx.x;                   // 0..63; XCD = r%8
    const int lo = r * RSIZE;
    for (int t = threadIdx.x; t < RSIZE; t += 1024) lcur[t] = 0;
    __syncthreads();
    for (int p = 0; p < 8; ++p) {
        int b = (p << 6) | r;
        int len = pcur[b];
        if (len > CAP) len = CAP;
        const int* bs = pair_s + (size_t)b * CAP;
        const int* bd = pair_d + (size_t)b * CAP;
        for (int i = threadIdx.x; i < len; i += 1024) {
            int d = bd[i];
            int lp = atomicAdd(&lcur[d - lo], 1);           // LDS atomic
            csr_src[row_start[d] + lp] = bs[i];             // write in 100KB XCD-local window
        }
    }
}

// ---------------- hierarchical scan: block sums ----------------
__global__ __launch_bounds__(256) void k_bsum(const int* __restrict__ deg, int* __restrict__ bsum) {
    int i = blockIdx.x * 256 + threadIdx.x;
    int v = (i < NN) ? deg[i] : 0;
    int lane = threadIdx.x & 63, wid = threadIdx.x >> 6;
#pragma unroll
    for (int d = 32; d; d >>= 1) v += __shfl_down(v, d, 64);
    __shared__ int wsum[4];
    if (lane == 0) wsum[wid] = v;
    __syncthreads();
    if (threadIdx.x == 0) bsum[blockIdx.x] = wsum[0] + wsum[1] + wsum[2] + wsum[3];
}

// ---------------- scan of 391 block sums (one block) ----------------
__global__ __launch_bounds__(512) void k_bscan(const int* __restrict__ bsum, int* __restrict__ boff,
                                               int* __restrict__ row_start) {
    __shared__ int s[512];
    int tid = threadIdx.x;
    int v = (tid < NB) ? bsum[tid] : 0;
    s[tid] = v;
    __syncthreads();
    for (int d = 1; d < 512; d <<= 1) {
        int t = (tid >= d) ? s[tid - d] : 0;
        __syncthreads();
        s[tid] += t;
        __syncthreads();
    }
    if (tid < NB) boff[tid] = s[tid] - v;   // exclusive
    if (tid == 0) row_start[NN] = EE;
}

// ---------------- final scan: row_start + deg_inv ----------------
__global__ __launch_bounds__(256) void k_scan2(const int* __restrict__ deg, const int* __restrict__ boff,
                                               int* __restrict__ row_start, float* __restrict__ deg_inv) {
    int tid = threadIdx.x, lane = tid & 63, wid = tid >> 6;
    int i = blockIdx.x * 256 + tid;
    int v = (i < NN) ? deg[i] : 0;
    int inc = v;
#pragma unroll
    for (int d = 1; d < 64; d <<= 1) {
        int t = __shfl_up(inc, d, 64);
        if (lane >= d) inc += t;
    }
    __shared__ int wsum[4];
    if (lane == 63) wsum[wid] = inc;
    __syncthreads();
    if (tid == 0) {
        int s = 0;
#pragma unroll
        for (int j = 0; j < 4; ++j) { int t = wsum[j]; wsum[j] = s; s += t; }
    }
    __syncthreads();
    if (i < NN) {
        row_start[i] = boff[blockIdx.x] + wsum[wid] + (inc - v);
        deg_inv[i] = (v > 0) ? 1.0f / (float)v : 0.0f;
    }
}

// ---------------- fp32 -> bf16 row convert (x: N x 40) ----------------
__global__ __launch_bounds__(256) void k_cvt(const float* __restrict__ x, unsigned short* __restrict__ xb) {
    int i = blockIdx.x * 256 + threadIdx.x;            // groups of 8 elems
    if (i >= NN * 40 / 8) return;
    const float4* p = (const float4*)(x + (size_t)i * 8);
    float4 a = p[0], b = p[1];
    short8 v;
    v[0] = (short)f2bf(a.x); v[1] = (short)f2bf(a.y); v[2] = (short)f2bf(a.z); v[3] = (short)f2bf(a.w);
    v[4] = (short)f2bf(b.x); v[5] = (short)f2bf(b.y); v[6] = (short)f2bf(b.z); v[7] = (short)f2bf(b.w);
    *(short8*)(xb + (size_t)i * 8) = v;
}

// ---------------- bf16 mean-aggregate into concat A = [mean(FinP) | root(FinP)] ----------------
template<int Fin, int FinP>
__global__ __launch_bounds__(256) void k_meanb(const unsigned short* __restrict__ xin,
                                               const int* __restrict__ row_start,
                                               const int* __restrict__ csr_src,
                                               const float* __restrict__ deg_inv,
                                               unsigned short* __restrict__ Acat) {
    constexpr int CH = Fin / 8;     // data chunks (5 or 8)
    constexpr int PCH = FinP / 8;   // padded chunks (6 or 8)
    constexpr int K2 = 2 * FinP;
    int gid = blockIdx.x * 256 + threadIdx.x;
    int node = gid >> 3;
    int c = gid & 7;
    if (node >= NN) return;
    float acc[8] = {0, 0, 0, 0, 0, 0, 0, 0};
    if (c < CH) {
        const unsigned short* xq = xin + c * 8;
        int rs = row_start[node], re = row_start[node + 1];
        int k = rs;
        for (; k + 4 <= re; k += 4) {
            int s0 = csr_src[k], s1 = csr_src[k + 1], s2 = csr_src[k + 2], s3 = csr_src[k + 3];
            short8 v0 = *(const short8*)(xq + (size_t)s0 * Fin);
            short8 v1 = *(const short8*)(xq + (size_t)s1 * Fin);
            short8 v2 = *(const short8*)(xq + (size_t)s2 * Fin);
            short8 v3 = *(const short8*)(xq + (size_t)s3 * Fin);
#pragma unroll
            for (int j = 0; j < 8; ++j)
                acc[j] += (bf2f((unsigned short)v0[j]) + bf2f((unsigned short)v1[j]))
                        + (bf2f((unsigned short)v2[j]) + bf2f((unsigned short)v3[j]));
        }
        for (; k < re; ++k) {
            short8 v0 = *(const short8*)(xq + (size_t)csr_src[k] * Fin);
#pragma unroll
            for (int j = 0; j < 8; ++j) acc[j] += bf2f((unsigned short)v0[j]);
        }
        float di = deg_inv[node];
#pragma unroll
        for (int j = 0; j < 8; ++j) acc[j] *= di;
    }
    if (c < PCH) {
        short8 m;
#pragma unroll
        for (int j = 0; j < 8; ++j) m[j] = (c < CH) ? (short)f2bf(acc[j]) : (short)0;
        *(short8*)(Acat + (size_t)node * K2 + c * 8) = m;
        short8 rv;
        if (c < CH) {
            rv = *(const short8*)(xin + (size_t)node * Fin + c * 8);
        } else {
#pragma unroll
            for (int j = 0; j < 8; ++j) rv[j] = 0;
        }
        *(short8*)(Acat + (size_t)node * K2 + FinP + c * 8) = rv;
    }
}

// ---------------- MFMA GEMM: out = relu?(A @ [Wl;Wr]^T + b), A = N x 2FinP bf16 ----------------
template<int Fin, int FinP, int Fout, bool RELU>
__global__ __launch_bounds__(256) void k_gemm(const unsigned short* __restrict__ A,
                                              const float* __restrict__ Wl,
                                              const float* __restrict__ bias,
                                              const float* __restrict__ Wr,
                                              unsigned short* __restrict__ out) {
    constexpr int K = 2 * FinP;
    constexpr int KS = K / 32;
    constexpr int TILES = Fout / 16;
    __shared__ short sB[TILES * KS * 64 * 8];
    const int lane = threadIdx.x & 63;
    for (int idx = threadIdx.x; idx < TILES * KS * 64; idx += 256) {
        int l = idx & 63;
        int ks = (idx >> 6) % KS;
        int t = idx / (64 * KS);
        int o = t * 16 + (l & 15);
        int kbase = ks * 32 + (l >> 4) * 8;
        short8 v;
#pragma unroll
        for (int j = 0; j < 8; ++j) {
            int k = kbase + j;
            float w;
            if (k < FinP) w = (k < Fin) ? Wl[(size_t)o * Fin + k] : 0.f;
            else { int k2 = k - FinP; w = (k2 < Fin) ? Wr[(size_t)o * Fin + k2] : 0.f; }
            v[j] = (short)f2bf(w);
        }
        *(short8*)&sB[idx * 8] = v;
    }
    __syncthreads();
    float bias_t[TILES];
#pragma unroll
    for (int t = 0; t < TILES; ++t) bias_t[t] = bias[t * 16 + (lane & 15)];

    const int wave = blockIdx.x * 4 + (threadIdx.x >> 6);
    const int nchunks = NN / 32;                        // 3125
    for (int ci = wave; ci < nchunks; ci += gridDim.x * 4) {
        int nbase = ci * 32;
        const unsigned short* a0 = A + (size_t)(nbase + (lane & 15)) * K + (lane >> 4) * 8;
        short8 af[2][KS];
#pragma unroll
        for (int ks = 0; ks < KS; ++ks) {
            af[0][ks] = *(const short8*)(a0 + ks * 32);
            af[1][ks] = *(const short8*)(a0 + 16 * K + ks * 32);
        }
        f32x4 acc[2][TILES];
#pragma unroll
        for (int m = 0; m < 2; ++m)
#pragma unroll
            for (int t = 0; t < TILES; ++t) acc[m][t] = (f32x4){0.f, 0.f, 0.f, 0.f};
#pragma unroll
        for (int t = 0; t < TILES; ++t)
#pragma unroll
            for (int ks = 0; ks < KS; ++ks) {
                short8 bf = *(const short8*)&sB[((t * KS + ks) * 64 + lane) * 8];
                acc[0][t] = __builtin_amdgcn_mfma_f32_16x16x32_bf16(af[0][ks], bf, acc[0][t], 0, 0, 0);
                acc[1][t] = __builtin_amdgcn_mfma_f32_16x16x32_bf16(af[1][ks], bf, acc[1][t], 0, 0, 0);
            }
#pragma unroll
        for (int m = 0; m < 2; ++m) {
            int nrow = nbase + m * 16 + (lane >> 4) * 4;
#pragma unroll
            for (int t = 0; t < TILES; ++t) {
                int col = t * 16 + (lane & 15);
#pragma unroll
                for (int r = 0; r < 4; ++r) {
                    float v = acc[m][t][r] + bias_t[t];
                    if (RELU) v = fmaxf(v, 0.f);
                    out[(size_t)(nrow + r) * Fout + col] = f2bf(v);
                }
            }
        }
    }
}

// ---------------- layer 3 transforms: z = h2@W4l.T, r = h2@W4r.T (h2 bf16) ----------------
__global__ __launch_bounds__(256) void k_zr(const unsigned short* __restrict__ h2,
                                            const float* __restrict__ W4l, const float* __restrict__ W4r,
                                            float* __restrict__ z, float* __restrict__ r) {
    int node = (blockIdx.x * 256 + threadIdx.x) >> 6;
    int lane = threadIdx.x & 63;
    if (node >= NN) return;
    float h0 = bf2f(h2[(size_t)node * 128 + lane]);
    float h1v = bf2f(h2[(size_t)node * 128 + 64 + lane]);
    float zc0 = h0 * W4l[0 * 128 + lane] + h1v * W4l[0 * 128 + 64 + lane];
    float zc1 = h0 * W4l[1 * 128 + lane] + h1v * W4l[1 * 128 + 64 + lane];
    float zc2 = h0 * W4l[2 * 128 + lane] + h1v * W4l[2 * 128 + 64 + lane];
    float rc0 = h0 * W4r[0 * 128 + lane] + h1v * W4r[0 * 128 + 64 + lane];
    float rc1 = h0 * W4r[1 * 128 + lane] + h1v * W4r[1 * 128 + 64 + lane];
    float rc2 = h0 * W4r[2 * 128 + lane] + h1v * W4r[2 * 128 + 64 + lane];
#pragma unroll
    for (int d = 32; d; d >>= 1) {
        zc0 += __shfl_down(zc0, d, 64); zc1 += __shfl_down(zc1, d, 64); zc2 += __shfl_down(zc2, d, 64);
        rc0 += __shfl_down(rc0, d, 64); rc1 += __shfl_down(rc1, d, 64); rc2 += __shfl_down(rc2, d, 64);
    }
    if (lane == 0) {
        *(float4*)&z[(size_t)node * 4] = make_float4(zc0, zc1, zc2, 0.f);
        *(float4*)&r[(size_t)node * 4] = make_float4(rc0, rc1, rc2, 0.f);
    }
}

// ---------------- final: out = mean(z)[n] + r[n] + b4 ----------------
__global__ __launch_bounds__(256) void k_final(const float* __restrict__ z, const float* __restrict__ r,
                                               const float* __restrict__ b4,
                                               const int* __restrict__ row_start, const int* __restrict__ csr_src,
                                               const float* __restrict__ deg_inv, float* __restrict__ out) {
    int n = blockIdx.x * 256 + threadIdx.x;
    if (n >= NN) return;
    int rs = row_start[n], re = row_start[n + 1];
    float a0 = 0, a1 = 0, a2 = 0, b0 = 0, b1 = 0, b2 = 0;
    int k = rs;
    for (; k + 4 <= re; k += 4) {
        int s0 = csr_src[k], s1 = csr_src[k + 1], s2 = csr_src[k + 2], s3 = csr_src[k + 3];
        float4 z0 = *(const float4*)&z[4 * (size_t)s0];
        float4 z1 = *(const float4*)&z[4 * (size_t)s1];
        float4 z2 = *(const float4*)&z[4 * (size_t)s2];
        float4 z3 = *(const float4*)&z[4 * (size_t)s3];
        a0 += z0.x; a1 += z0.y; a2 += z0.z;
        b0 += z1.x; b1 += z1.y; b2 += z1.z;
        a0 += z2.x; a1 += z2.y; a2 += z2.z;
        b0 += z3.x; b1 += z3.y; b2 += z3.z;
    }
    for (; k < re; ++k) {
        float4 z0 = *(const float4*)&z[4 * (size_t)csr_src[k]];
        a0 += z0.x; a1 += z0.y; a2 += z0.z;
    }
    float di = deg_inv[n];
    float4 rn = *(const float4*)&r[4 * (size_t)n];
    out[(size_t)n * 3 + 0] = (a0 + b0) * di + rn.x + b4[0];
    out[(size_t)n * 3 + 1] = (a1 + b1) * di + rn.y + b4[1];
    out[(size_t)n * 3 + 2] = (a2 + b2) * di + rn.z + b4[2];
}

extern "C" void kernel_launch(void* const* d_in, const int* in_sizes, int n_in,
                              void* d_out, int out_size, void* d_ws, size_t ws_size,
                              hipStream_t stream) {
    const float* x   = (const float*)d_in[0];
    const int*   ei  = (const int*)d_in[1];
    const float* W1l = (const float*)d_in[2];
    const float* b1  = (const float*)d_in[3];
    const float* W1r = (const float*)d_in[4];
    const float* W2l = (const float*)d_in[5];
    const float* b2  = (const float*)d_in[6];
    const float* W2r = (const float*)d_in[7];
    const float* W4l = (const float*)d_in[8];
    const float* b4  = (const float*)d_in[9];
    const float* W4r = (const float*)d_in[10];
    float* out = (float*)d_out;

    char* ws = (char*)d_ws;
    size_t off = 0;
    auto alloc = [&](size_t bytes) -> void* {
        void* p = ws + off;
        off = (off + bytes + 255) & ~(size_t)255;
        return p;
    };
    int*   deg       = (int*)alloc((size_t)NN * 4);
    int*   row_start = (int*)alloc(((size_t)NN + 1) * 4);
    int*   csr_src   = (int*)alloc((size_t)EE * 4);
    float* deg_inv   = (float*)alloc((size_t)NN * 4);
    int*   bsum      = (int*)alloc((size_t)NB * 4);
    int*   boff      = (int*)alloc((size_t)NB * 4);
    int*   pcur      = (int*)alloc((size_t)NBUCKET * 4);
    unsigned short* xb    = (unsigned short*)alloc((size_t)NN * 40 * 2);
    unsigned short* A1cat = (unsigned short*)alloc((size_t)NN * 96 * 2);
    unsigned short* h1    = (unsigned short*)alloc((size_t)NN * 64 * 2);
    unsigned short* A2cat = (unsigned short*)alloc((size_t)NN * 128 * 2);  // 25.6 MB
    unsigned short* h2    = (unsigned short*)alloc((size_t)NN * 128 * 2);
    float* zbuf = (float*)alloc((size_t)NN * 4 * 4);
    float* rbuf = (float*)alloc((size_t)NN * 4 * 4);
    // pair_s/pair_d (8.4 MB each) alias A2cat (25.6 MB): dead before A2cat
    // first written (layer-2 k_meanb).
    int* pair_s = (int*)A2cat;
    int* pair_d = pair_s + (size_t)NBUCKET * CAP;

    const int* e_src = ei;
    const int* e_dst = ei + EE;

    hipMemsetAsync(pcur, 0, (size_t)NBUCKET * 4, stream);

    // phase 1: bucket (block-local reservation; zero per-edge global atomics)
    k_bucket<<<BUCKET_BLOCKS, 256, 0, stream>>>(e_src, e_dst, pcur, pair_s, pair_d);
    k_cvt<<<((NN * 40 / 8) + 255) / 256, 256, 0, stream>>>(x, xb);
    // phase 1.5: per-range LDS degree count
    k_degr<<<NRANGE, 1024, 0, stream>>>(pair_d, pcur, deg);
    k_bsum<<<NB, 256, 0, stream>>>(deg, bsum);
    k_bscan<<<1, 512, 0, stream>>>(bsum, boff, row_start);
    k_scan2<<<NB, 256, 0, stream>>>(deg, boff, row_start, deg_inv);
    // phase 2: scatter with per-range LDS cursors
    k_scatter2<<<NRANGE, 1024, 0, stream>>>(pair_s, pair_d, pcur, row_start, csr_src);

    const int mean_blocks = ((size_t)NN * 8 + 255) / 256;   // 3125
    const int gemm_blocks = 782;

    // layer 1: 40 -> 64  (K = 2*48 = 96)
    k_meanb<40, 48><<<mean_blocks, 256, 0, stream>>>(xb, row_start, csr_src, deg_inv, A1cat);
    k_gemm<40, 48, 64, true><<<gemm_blocks, 256, 0, stream>>>(A1cat, W1l, b1, W1r, h1);

    // layer 2: 64 -> 128  (K = 128)
    k_meanb<64, 64><<<mean_blocks, 256, 0, stream>>>(h1, row_start, csr_src, deg_inv, A2cat);
    k_gemm<64, 64, 128, true><<<gemm_blocks, 256, 0, stream>>>(A2cat, W2l, b2, W2r, h2);

    // layer 3: 128 -> 3, transform-before-gather
    k_zr<<<((size_t)NN * 64 + 255) / 256, 256, 0, stream>>>(h2, W4l, W4r, zbuf, rbuf);
    k_final<<<(NN + 255) / 256, 256, 0, stream>>>(zbuf, rbuf, b4, row_start, csr_src, deg_inv, out);
}

// Round 13
// 286.686 us; speedup vs baseline: 3.1348x; 1.0985x over previous
//
#include <hip/hip_runtime.h>
#include <hip/hip_bf16.h>

// GraphSAGE 3-layer: 40 -> 64 -> 128 -> 3, mean aggregation over fixed edges.
// R13: k_zr (42.6us, one wave/node + 36-deep shuffle chain, 600 GB/s) replaced
// by a narrow MFMA GEMM: z,r = h2 @ [W4l|pad|W4r]^T (128x16, cols 0-2=z,
// 4-6=r). Same fragment machinery as k_gemm (verified). Rest = R12.

static constexpr int NN = 100000;
static constexpr int EE = 1600000;
static constexpr int NB = (NN + 255) / 256;   // 391 scan blocks
static constexpr int NRANGE = 64;
static constexpr int RSIZE = (NN + NRANGE - 1) / NRANGE;   // 1563
static constexpr int NBUCKET = 8 * NRANGE;                 // 512
static constexpr int CAP = 4096;     // per-bucket capacity (mean ~3130, ~17 sigma)
static constexpr int BCHUNK = 2048;  // edges per block (8 per thread)
static constexpr int BUCKET_BLOCKS = (EE + BCHUNK - 1) / BCHUNK;  // 782

typedef __attribute__((ext_vector_type(8))) short short8;
typedef __attribute__((ext_vector_type(4))) float f32x4;

__device__ __forceinline__ float bf2f(unsigned short u) {
    union { unsigned int i; float f; } c; c.i = ((unsigned int)u) << 16; return c.f;
}
__device__ __forceinline__ unsigned short f2bf(float f) {
    union { float f; unsigned int i; } c; c.f = f;
    unsigned int x = c.i;
    return (unsigned short)((x + 0x7fffu + ((x >> 16) & 1u)) >> 16);   // RNE
}

// ---------------- phase 1: bucket edges by (xcd, dst-range), block-local reservation ----------------
__global__ __launch_bounds__(256) void k_bucket(const int* __restrict__ src, const int* __restrict__ dst,
                                                int* __restrict__ pcur,
                                                int* __restrict__ pair_s, int* __restrict__ pair_d) {
    __shared__ int cnt[NRANGE];
    __shared__ int base[NRANGE];
    const int part = blockIdx.x & 7;            // this block's XCD tag (round-robin)
    const int e0 = blockIdx.x * BCHUNK;
    const int tid = threadIdx.x;
    if (tid < NRANGE) cnt[tid] = 0;
    __syncthreads();
    int r_[8], lp_[8], s_[8], d_[8];
#pragma unroll
    for (int j = 0; j < 8; ++j) {
        int e = e0 + j * 256 + tid;
        r_[j] = -1;
        if (e < EE) {
            int d = dst[e];
            int s = src[e];
            int r = d / RSIZE;                  // const-divide -> magic mul
            r_[j] = r; s_[j] = s; d_[j] = d;
            lp_[j] = atomicAdd(&cnt[r], 1);     // fast LDS atomic
        }
    }
    __syncthreads();
    if (tid < NRANGE) {
        int c = cnt[tid];
        base[tid] = (c > 0) ? atomicAdd(&pcur[(part << 6) | tid], c) : 0;  // 1 global RMW / bucket / block
    }
    __syncthreads();
#pragma unroll
    for (int j = 0; j < 8; ++j) {
        if (r_[j] >= 0) {
            int pos = base[r_[j]] + lp_[j];
            if (pos < CAP) {
                size_t idx = (size_t)((part << 6) | r_[j]) * CAP + pos;
                pair_s[idx] = s_[j];
                pair_d[idx] = d_[j];
            }
        }
    }
}

// ---------------- phase 1.5: per-range degree count in LDS (no global atomics) ----------------
__global__ __launch_bounds__(1024) void k_degr(const int* __restrict__ pair_d, const int* __restrict__ pcur,
                                               int* __restrict__ deg) {
    __shared__ int ldeg[RSIZE];
    const int r = blockIdx.x;                   // 0..63; XCD = r%8
    const int lo = r * RSIZE;
    const int hi = (lo + RSIZE < NN) ? lo + RSIZE : NN;
    for (int t = threadIdx.x; t < RSIZE; t += 1024) ldeg[t] = 0;
    __syncthreads();
    for (int p = 0; p < 8; ++p) {
        int b = (p << 6) | r;
        int len = pcur[b];
        if (len > CAP) len = CAP;
        const int* base = pair_d + (size_t)b * CAP;
        for (int i = threadIdx.x; i < len; i += 1024)
            atomicAdd(&ldeg[base[i] - lo], 1);
    }
    __syncthreads();
    for (int t = threadIdx.x; t < hi - lo; t += 1024)
        deg[lo + t] = ldeg[t];                  // coalesced full-line write, once
}

// ---------------- phase 2: scatter into CSR with per-range LDS cursors ----------------
__global__ __launch_bounds__(1024) void k_scatter2(const int* __restrict__ pair_s, const int* __restrict__ pair_d,
                                                   const int* __restrict__ pcur,
                                                   const int* __restrict__ row_start,
                                                   int* __restrict__ csr_src) {
    __shared__ int lcur[RSIZE];
    const int r = blockIdx.x;                   // 0..63; XCD = r%8
    const int lo = r * RSIZE;
    for (int t = threadIdx.x; t < RSIZE; t += 1024) lcur[t] = 0;
    __syncthreads();
    for (int p = 0; p < 8; ++p) {
        int b = (p << 6) | r;
        int len = pcur[b];
        if (len > CAP) len = CAP;
        const int* bs = pair_s + (size_t)b * CAP;
        const int* bd = pair_d + (size_t)b * CAP;
        for (int i = threadIdx.x; i < len; i += 1024) {
            int d = bd[i];
            int lp = atomicAdd(&lcur[d - lo], 1);           // LDS atomic
            csr_src[row_start[d] + lp] = bs[i];             // write in 100KB XCD-local window
        }
    }
}

// ---------------- hierarchical scan: block sums ----------------
__global__ __launch_bounds__(256) void k_bsum(const int* __restrict__ deg, int* __restrict__ bsum) {
    int i = blockIdx.x * 256 + threadIdx.x;
    int v = (i < NN) ? deg[i] : 0;
    int lane = threadIdx.x & 63, wid = threadIdx.x >> 6;
#pragma unroll
    for (int d = 32; d; d >>= 1) v += __shfl_down(v, d, 64);
    __shared__ int wsum[4];
    if (lane == 0) wsum[wid] = v;
    __syncthreads();
    if (threadIdx.x == 0) bsum[blockIdx.x] = wsum[0] + wsum[1] + wsum[2] + wsum[3];
}

// ---------------- scan of 391 block sums (one block) ----------------
__global__ __launch_bounds__(512) void k_bscan(const int* __restrict__ bsum, int* __restrict__ boff,
                                               int* __restrict__ row_start) {
    __shared__ int s[512];
    int tid = threadIdx.x;
    int v = (tid < NB) ? bsum[tid] : 0;
    s[tid] = v;
    __syncthreads();
    for (int d = 1; d < 512; d <<= 1) {
        int t = (tid >= d) ? s[tid - d] : 0;
        __syncthreads();
        s[tid] += t;
        __syncthreads();
    }
    if (tid < NB) boff[tid] = s[tid] - v;   // exclusive
    if (tid == 0) row_start[NN] = EE;
}

// ---------------- final scan: row_start + deg_inv ----------------
__global__ __launch_bounds__(256) void k_scan2(const int* __restrict__ deg, const int* __restrict__ boff,
                                               int* __restrict__ row_start, float* __restrict__ deg_inv) {
    int tid = threadIdx.x, lane = tid & 63, wid = tid >> 6;
    int i = blockIdx.x * 256 + tid;
    int v = (i < NN) ? deg[i] : 0;
    int inc = v;
#pragma unroll
    for (int d = 1; d < 64; d <<= 1) {
        int t = __shfl_up(inc, d, 64);
        if (lane >= d) inc += t;
    }
    __shared__ int wsum[4];
    if (lane == 63) wsum[wid] = inc;
    __syncthreads();
    if (tid == 0) {
        int s = 0;
#pragma unroll
        for (int j = 0; j < 4; ++j) { int t = wsum[j]; wsum[j] = s; s += t; }
    }
    __syncthreads();
    if (i < NN) {
        row_start[i] = boff[blockIdx.x] + wsum[wid] + (inc - v);
        deg_inv[i] = (v > 0) ? 1.0f / (float)v : 0.0f;
    }
}

// ---------------- fp32 -> bf16 row convert (x: N x 40) ----------------
__global__ __launch_bounds__(256) void k_cvt(const float* __restrict__ x, unsigned short* __restrict__ xb) {
    int i = blockIdx.x * 256 + threadIdx.x;            // groups of 8 elems
    if (i >= NN * 40 / 8) return;
    const float4* p = (const float4*)(x + (size_t)i * 8);
    float4 a = p[0], b = p[1];
    short8 v;
    v[0] = (short)f2bf(a.x); v[1] = (short)f2bf(a.y); v[2] = (short)f2bf(a.z); v[3] = (short)f2bf(a.w);
    v[4] = (short)f2bf(b.x); v[5] = (short)f2bf(b.y); v[6] = (short)f2bf(b.z); v[7] = (short)f2bf(b.w);
    *(short8*)(xb + (size_t)i * 8) = v;
}

// ---------------- bf16 mean-aggregate into concat A = [mean(FinP) | root(FinP)] ----------------
template<int Fin, int FinP>
__global__ __launch_bounds__(256) void k_meanb(const unsigned short* __restrict__ xin,
                                               const int* __restrict__ row_start,
                                               const int* __restrict__ csr_src,
                                               const float* __restrict__ deg_inv,
                                               unsigned short* __restrict__ Acat) {
    constexpr int CH = Fin / 8;     // data chunks (5 or 8)
    constexpr int PCH = FinP / 8;   // padded chunks (6 or 8)
    constexpr int K2 = 2 * FinP;
    int gid = blockIdx.x * 256 + threadIdx.x;
    int node = gid >> 3;
    int c = gid & 7;
    if (node >= NN) return;
    float acc[8] = {0, 0, 0, 0, 0, 0, 0, 0};
    if (c < CH) {
        const unsigned short* xq = xin + c * 8;
        int rs = row_start[node], re = row_start[node + 1];
        int k = rs;
        for (; k + 4 <= re; k += 4) {
            int s0 = csr_src[k], s1 = csr_src[k + 1], s2 = csr_src[k + 2], s3 = csr_src[k + 3];
            short8 v0 = *(const short8*)(xq + (size_t)s0 * Fin);
            short8 v1 = *(const short8*)(xq + (size_t)s1 * Fin);
            short8 v2 = *(const short8*)(xq + (size_t)s2 * Fin);
            short8 v3 = *(const short8*)(xq + (size_t)s3 * Fin);
#pragma unroll
            for (int j = 0; j < 8; ++j)
                acc[j] += (bf2f((unsigned short)v0[j]) + bf2f((unsigned short)v1[j]))
                        + (bf2f((unsigned short)v2[j]) + bf2f((unsigned short)v3[j]));
        }
        for (; k < re; ++k) {
            short8 v0 = *(const short8*)(xq + (size_t)csr_src[k] * Fin);
#pragma unroll
            for (int j = 0; j < 8; ++j) acc[j] += bf2f((unsigned short)v0[j]);
        }
        float di = deg_inv[node];
#pragma unroll
        for (int j = 0; j < 8; ++j) acc[j] *= di;
    }
    if (c < PCH) {
        short8 m;
#pragma unroll
        for (int j = 0; j < 8; ++j) m[j] = (c < CH) ? (short)f2bf(acc[j]) : (short)0;
        *(short8*)(Acat + (size_t)node * K2 + c * 8) = m;
        short8 rv;
        if (c < CH) {
            rv = *(const short8*)(xin + (size_t)node * Fin + c * 8);
        } else {
#pragma unroll
            for (int j = 0; j < 8; ++j) rv[j] = 0;
        }
        *(short8*)(Acat + (size_t)node * K2 + FinP + c * 8) = rv;
    }
}

// ---------------- MFMA GEMM: out = relu?(A @ [Wl;Wr]^T + b), A = N x 2FinP bf16 ----------------
template<int Fin, int FinP, int Fout, bool RELU>
__global__ __launch_bounds__(256) void k_gemm(const unsigned short* __restrict__ A,
                                              const float* __restrict__ Wl,
                                              const float* __restrict__ bias,
                                              const float* __restrict__ Wr,
                                              unsigned short* __restrict__ out) {
    constexpr int K = 2 * FinP;
    constexpr int KS = K / 32;
    constexpr int TILES = Fout / 16;
    __shared__ short sB[TILES * KS * 64 * 8];
    const int lane = threadIdx.x & 63;
    for (int idx = threadIdx.x; idx < TILES * KS * 64; idx += 256) {
        int l = idx & 63;
        int ks = (idx >> 6) % KS;
        int t = idx / (64 * KS);
        int o = t * 16 + (l & 15);
        int kbase = ks * 32 + (l >> 4) * 8;
        short8 v;
#pragma unroll
        for (int j = 0; j < 8; ++j) {
            int k = kbase + j;
            float w;
            if (k < FinP) w = (k < Fin) ? Wl[(size_t)o * Fin + k] : 0.f;
            else { int k2 = k - FinP; w = (k2 < Fin) ? Wr[(size_t)o * Fin + k2] : 0.f; }
            v[j] = (short)f2bf(w);
        }
        *(short8*)&sB[idx * 8] = v;
    }
    __syncthreads();
    float bias_t[TILES];
#pragma unroll
    for (int t = 0; t < TILES; ++t) bias_t[t] = bias[t * 16 + (lane & 15)];

    const int wave = blockIdx.x * 4 + (threadIdx.x >> 6);
    const int nchunks = NN / 32;                        // 3125
    for (int ci = wave; ci < nchunks; ci += gridDim.x * 4) {
        int nbase = ci * 32;
        const unsigned short* a0 = A + (size_t)(nbase + (lane & 15)) * K + (lane >> 4) * 8;
        short8 af[2][KS];
#pragma unroll
        for (int ks = 0; ks < KS; ++ks) {
            af[0][ks] = *(const short8*)(a0 + ks * 32);
            af[1][ks] = *(const short8*)(a0 + 16 * K + ks * 32);
        }
        f32x4 acc[2][TILES];
#pragma unroll
        for (int m = 0; m < 2; ++m)
#pragma unroll
            for (int t = 0; t < TILES; ++t) acc[m][t] = (f32x4){0.f, 0.f, 0.f, 0.f};
#pragma unroll
        for (int t = 0; t < TILES; ++t)
#pragma unroll
            for (int ks = 0; ks < KS; ++ks) {
                short8 bf = *(const short8*)&sB[((t * KS + ks) * 64 + lane) * 8];
                acc[0][t] = __builtin_amdgcn_mfma_f32_16x16x32_bf16(af[0][ks], bf, acc[0][t], 0, 0, 0);
                acc[1][t] = __builtin_amdgcn_mfma_f32_16x16x32_bf16(af[1][ks], bf, acc[1][t], 0, 0, 0);
            }
#pragma unroll
        for (int m = 0; m < 2; ++m) {
            int nrow = nbase + m * 16 + (lane >> 4) * 4;
#pragma unroll
            for (int t = 0; t < TILES; ++t) {
                int col = t * 16 + (lane & 15);
#pragma unroll
                for (int r = 0; r < 4; ++r) {
                    float v = acc[m][t][r] + bias_t[t];
                    if (RELU) v = fmaxf(v, 0.f);
                    out[(size_t)(nrow + r) * Fout + col] = f2bf(v);
                }
            }
        }
    }
}

// ---------------- layer 3 transform via narrow MFMA: [z|r] = h2 @ B (128x16) ----------------
// B cols 0-2 = W4l rows, cols 4-6 = W4r rows, rest zero. C layout: col=lane&15,
// row=(lane>>4)*4+reg (same mapping as k_gemm, verified).
__global__ __launch_bounds__(256) void k_zr_mfma(const unsigned short* __restrict__ h2,
                                                 const float* __restrict__ W4l, const float* __restrict__ W4r,
                                                 float* __restrict__ z, float* __restrict__ r) {
    __shared__ short sB[4 * 64 * 8];           // 4 ks-frags
    {
        int idx = threadIdx.x;                 // 256 = 4*64 entries exactly
        int l = idx & 63;
        int ks = idx >> 6;
        int o = l & 15;
        int kbase = ks * 32 + (l >> 4) * 8;
        short8 v;
#pragma unroll
        for (int j = 0; j < 8; ++j) {
            int k = kbase + j;
            float w = 0.f;
            if (o < 3) w = W4l[o * 128 + k];
            else if (o >= 4 && o < 7) w = W4r[(o - 4) * 128 + k];
            v[j] = (short)f2bf(w);
        }
        *(short8*)&sB[idx * 8] = v;
    }
    __syncthreads();
    const int lane = threadIdx.x & 63;
    short8 bf[4];
#pragma unroll
    for (int ks = 0; ks < 4; ++ks) bf[ks] = *(const short8*)&sB[(ks * 64 + lane) * 8];

    const int col = lane & 15;
    const int rbase = (lane >> 4) * 4;
    const int wave = blockIdx.x * 4 + (threadIdx.x >> 6);
    const int nchunks = NN / 32;               // 3125
    for (int ci = wave; ci < nchunks; ci += gridDim.x * 4) {
        int nbase = ci * 32;
        const unsigned short* a0 = h2 + (size_t)(nbase + (lane & 15)) * 128 + (lane >> 4) * 8;
        f32x4 acc0 = (f32x4){0.f, 0.f, 0.f, 0.f};
        f32x4 acc1 = (f32x4){0.f, 0.f, 0.f, 0.f};
#pragma unroll
        for (int ks = 0; ks < 4; ++ks) {
            short8 af0 = *(const short8*)(a0 + ks * 32);
            short8 af1 = *(const short8*)(a0 + 16 * 128 + ks * 32);
            acc0 = __builtin_amdgcn_mfma_f32_16x16x32_bf16(af0, bf[ks], acc0, 0, 0, 0);
            acc1 = __builtin_amdgcn_mfma_f32_16x16x32_bf16(af1, bf[ks], acc1, 0, 0, 0);
        }
#pragma unroll
        for (int m = 0; m < 2; ++m) {
            f32x4 a = m ? acc1 : acc0;
            int nr = nbase + m * 16 + rbase;
            if (col < 3) {
#pragma unroll
                for (int q = 0; q < 4; ++q) z[(size_t)(nr + q) * 4 + col] = a[q];
            } else if (col >= 4 && col < 7) {
#pragma unroll
                for (int q = 0; q < 4; ++q) r[(size_t)(nr + q) * 4 + col - 4] = a[q];
            }
        }
    }
}

// ---------------- final: out = mean(z)[n] + r[n] + b4 ----------------
__global__ __launch_bounds__(256) void k_final(const float* __restrict__ z, const float* __restrict__ r,
                                               const float* __restrict__ b4,
                                               const int* __restrict__ row_start, const int* __restrict__ csr_src,
                                               const float* __restrict__ deg_inv, float* __restrict__ out) {
    int n = blockIdx.x * 256 + threadIdx.x;
    if (n >= NN) return;
    int rs = row_start[n], re = row_start[n + 1];
    float a0 = 0, a1 = 0, a2 = 0, b0 = 0, b1 = 0, b2 = 0;
    int k = rs;
    for (; k + 4 <= re; k += 4) {
        int s0 = csr_src[k], s1 = csr_src[k + 1], s2 = csr_src[k + 2], s3 = csr_src[k + 3];
        float4 z0 = *(const float4*)&z[4 * (size_t)s0];
        float4 z1 = *(const float4*)&z[4 * (size_t)s1];
        float4 z2 = *(const float4*)&z[4 * (size_t)s2];
        float4 z3 = *(const float4*)&z[4 * (size_t)s3];
        a0 += z0.x; a1 += z0.y; a2 += z0.z;
        b0 += z1.x; b1 += z1.y; b2 += z1.z;
        a0 += z2.x; a1 += z2.y; a2 += z2.z;
        b0 += z3.x; b1 += z3.y; b2 += z3.z;
    }
    for (; k < re; ++k) {
        float4 z0 = *(const float4*)&z[4 * (size_t)csr_src[k]];
        a0 += z0.x; a1 += z0.y; a2 += z0.z;
    }
    float di = deg_inv[n];
    float4 rn = *(const float4*)&r[4 * (size_t)n];
    out[(size_t)n * 3 + 0] = (a0 + b0) * di + rn.x + b4[0];
    out[(size_t)n * 3 + 1] = (a1 + b1) * di + rn.y + b4[1];
    out[(size_t)n * 3 + 2] = (a2 + b2) * di + rn.z + b4[2];
}

extern "C" void kernel_launch(void* const* d_in, const int* in_sizes, int n_in,
                              void* d_out, int out_size, void* d_ws, size_t ws_size,
                              hipStream_t stream) {
    const float* x   = (const float*)d_in[0];
    const int*   ei  = (const int*)d_in[1];
    const float* W1l = (const float*)d_in[2];
    const float* b1  = (const float*)d_in[3];
    const float* W1r = (const float*)d_in[4];
    const float* W2l = (const float*)d_in[5];
    const float* b2  = (const float*)d_in[6];
    const float* W2r = (const float*)d_in[7];
    const float* W4l = (const float*)d_in[8];
    const float* b4  = (const float*)d_in[9];
    const float* W4r = (const float*)d_in[10];
    float* out = (float*)d_out;

    char* ws = (char*)d_ws;
    size_t off = 0;
    auto alloc = [&](size_t bytes) -> void* {
        void* p = ws + off;
        off = (off + bytes + 255) & ~(size_t)255;
        return p;
    };
    int*   deg       = (int*)alloc((size_t)NN * 4);
    int*   row_start = (int*)alloc(((size_t)NN + 1) * 4);
    int*   csr_src   = (int*)alloc((size_t)EE * 4);
    float* deg_inv   = (float*)alloc((size_t)NN * 4);
    int*   bsum      = (int*)alloc((size_t)NB * 4);
    int*   boff      = (int*)alloc((size_t)NB * 4);
    int*   pcur      = (int*)alloc((size_t)NBUCKET * 4);
    unsigned short* xb    = (unsigned short*)alloc((size_t)NN * 40 * 2);
    unsigned short* A1cat = (unsigned short*)alloc((size_t)NN * 96 * 2);
    unsigned short* h1    = (unsigned short*)alloc((size_t)NN * 64 * 2);
    unsigned short* A2cat = (unsigned short*)alloc((size_t)NN * 128 * 2);  // 25.6 MB
    unsigned short* h2    = (unsigned short*)alloc((size_t)NN * 128 * 2);
    float* zbuf = (float*)alloc((size_t)NN * 4 * 4);
    float* rbuf = (float*)alloc((size_t)NN * 4 * 4);
    // pair_s/pair_d (8.4 MB each) alias A2cat (25.6 MB): dead before A2cat
    // first written (layer-2 k_meanb).
    int* pair_s = (int*)A2cat;
    int* pair_d = pair_s + (size_t)NBUCKET * CAP;

    const int* e_src = ei;
    const int* e_dst = ei + EE;

    hipMemsetAsync(pcur, 0, (size_t)NBUCKET * 4, stream);

    // phase 1: bucket (block-local reservation; zero per-edge global atomics)
    k_bucket<<<BUCKET_BLOCKS, 256, 0, stream>>>(e_src, e_dst, pcur, pair_s, pair_d);
    k_cvt<<<((NN * 40 / 8) + 255) / 256, 256, 0, stream>>>(x, xb);
    // phase 1.5: per-range LDS degree count
    k_degr<<<NRANGE, 1024, 0, stream>>>(pair_d, pcur, deg);
    k_bsum<<<NB, 256, 0, stream>>>(deg, bsum);
    k_bscan<<<1, 512, 0, stream>>>(bsum, boff, row_start);
    k_scan2<<<NB, 256, 0, stream>>>(deg, boff, row_start, deg_inv);
    // phase 2: scatter with per-range LDS cursors
    k_scatter2<<<NRANGE, 1024, 0, stream>>>(pair_s, pair_d, pcur, row_start, csr_src);

    const int mean_blocks = ((size_t)NN * 8 + 255) / 256;   // 3125
    const int gemm_blocks = 782;

    // layer 1: 40 -> 64  (K = 2*48 = 96)
    k_meanb<40, 48><<<mean_blocks, 256, 0, stream>>>(xb, row_start, csr_src, deg_inv, A1cat);
    k_gemm<40, 48, 64, true><<<gemm_blocks, 256, 0, stream>>>(A1cat, W1l, b1, W1r, h1);

    // layer 2: 64 -> 128  (K = 128)
    k_meanb<64, 64><<<mean_blocks, 256, 0, stream>>>(h1, row_start, csr_src, deg_inv, A2cat);
    k_gemm<64, 64, 128, true><<<gemm_blocks, 256, 0, stream>>>(A2cat, W2l, b2, W2r, h2);

    // layer 3: 128 -> 3, transform-before-gather (narrow MFMA)
    k_zr_mfma<<<gemm_blocks, 256, 0, stream>>>(h2, W4l, W4r, zbuf, rbuf);
    k_final<<<(NN + 255) / 256, 256, 0, stream>>>(zbuf, rbuf, b4, row_start, csr_src, deg_inv, out);
}

// Round 14
// 270.725 us; speedup vs baseline: 3.3196x; 1.0590x over previous
//
#include <hip/hip_runtime.h>
#include <hip/hip_bf16.h>

// GraphSAGE 3-layer: 40 -> 64 -> 128 -> 3, mean aggregation over fixed edges.
// R14: traffic + dispatch cuts on the R13 structure:
//  - pairs packed into one int (s:17b | dloc:11b): halves bucket stores.
//  - Acat eliminated: k_gemm reads mean (NN x 64, zero-padded) + root direct
//    from xb/h1 with guarded zero chunks (K=128 unchanged).
//  - k_cvt fused into k_bucket's dispatch (independent blocks).

static constexpr int NN = 100000;
static constexpr int EE = 1600000;
static constexpr int NB = (NN + 255) / 256;   // 391 scan blocks
static constexpr int NRANGE = 64;
static constexpr int RSIZE = (NN + NRANGE - 1) / NRANGE;   // 1563 (< 2^11)
static constexpr int NBUCKET = 8 * NRANGE;                 // 512
static constexpr int CAP = 4096;     // per-bucket capacity (mean ~3130, ~17 sigma)
static constexpr int BCHUNK = 2048;  // edges per block (8 per thread)
static constexpr int BUCKET_BLOCKS = (EE + BCHUNK - 1) / BCHUNK;  // 782
static constexpr int CVT_BLOCKS = (NN * 40 / 8 + 255) / 256;      // 1954

typedef __attribute__((ext_vector_type(8))) short short8;
typedef __attribute__((ext_vector_type(4))) float f32x4;

__device__ __forceinline__ float bf2f(unsigned short u) {
    union { unsigned int i; float f; } c; c.i = ((unsigned int)u) << 16; return c.f;
}
__device__ __forceinline__ unsigned short f2bf(float f) {
    union { float f; unsigned int i; } c; c.f = f;
    unsigned int x = c.i;
    return (unsigned short)((x + 0x7fffu + ((x >> 16) & 1u)) >> 16);   // RNE
}

// ---------------- phase 1 (fused): bucket edges (packed) + x->bf16 convert ----------------
__global__ __launch_bounds__(256) void k_bucket_cvt(const int* __restrict__ src, const int* __restrict__ dst,
                                                    int* __restrict__ pcur, unsigned int* __restrict__ pairs,
                                                    const float* __restrict__ x, unsigned short* __restrict__ xb) {
    __shared__ int cnt[NRANGE];
    __shared__ int base[NRANGE];
    const int tid = threadIdx.x;
    if (blockIdx.x >= BUCKET_BLOCKS) {
        // ---- convert branch: fp32 -> bf16 rows of x ----
        int i = (blockIdx.x - BUCKET_BLOCKS) * 256 + tid;
        if (i < NN * 40 / 8) {
            const float4* p = (const float4*)(x + (size_t)i * 8);
            float4 a = p[0], b = p[1];
            short8 v;
            v[0] = (short)f2bf(a.x); v[1] = (short)f2bf(a.y); v[2] = (short)f2bf(a.z); v[3] = (short)f2bf(a.w);
            v[4] = (short)f2bf(b.x); v[5] = (short)f2bf(b.y); v[6] = (short)f2bf(b.z); v[7] = (short)f2bf(b.w);
            *(short8*)(xb + (size_t)i * 8) = v;
        }
        return;
    }
    // ---- bucket branch: block-local reservation, packed (s | dloc<<17) ----
    const int part = blockIdx.x & 7;            // this block's XCD tag (round-robin)
    const int e0 = blockIdx.x * BCHUNK;
    if (tid < NRANGE) cnt[tid] = 0;
    __syncthreads();
    int r_[8], lp_[8];
    unsigned int p_[8];
#pragma unroll
    for (int j = 0; j < 8; ++j) {
        int e = e0 + j * 256 + tid;
        r_[j] = -1;
        if (e < EE) {
            int d = dst[e];
            int s = src[e];
            int r = d / RSIZE;                  // const-divide -> magic mul
            r_[j] = r;
            p_[j] = (unsigned int)s | ((unsigned int)(d - r * RSIZE) << 17);
            lp_[j] = atomicAdd(&cnt[r], 1);     // fast LDS atomic
        }
    }
    __syncthreads();
    if (tid < NRANGE) {
        int c = cnt[tid];
        base[tid] = (c > 0) ? atomicAdd(&pcur[(part << 6) | tid], c) : 0;  // 1 global RMW / bucket / block
    }
    __syncthreads();
#pragma unroll
    for (int j = 0; j < 8; ++j) {
        if (r_[j] >= 0) {
            int pos = base[r_[j]] + lp_[j];
            if (pos < CAP) pairs[(size_t)((part << 6) | r_[j]) * CAP + pos] = p_[j];
        }
    }
}

// ---------------- phase 1.5: per-range degree count in LDS (no global atomics) ----------------
__global__ __launch_bounds__(1024) void k_degr(const unsigned int* __restrict__ pairs, const int* __restrict__ pcur,
                                               int* __restrict__ deg) {
    __shared__ int ldeg[RSIZE];
    const int r = blockIdx.x;                   // 0..63; XCD = r%8
    const int lo = r * RSIZE;
    const int hi = (lo + RSIZE < NN) ? lo + RSIZE : NN;
    for (int t = threadIdx.x; t < RSIZE; t += 1024) ldeg[t] = 0;
    __syncthreads();
    for (int p = 0; p < 8; ++p) {
        int b = (p << 6) | r;
        int len = pcur[b];
        if (len > CAP) len = CAP;
        const unsigned int* base = pairs + (size_t)b * CAP;
        for (int i = threadIdx.x; i < len; i += 1024)
            atomicAdd(&ldeg[base[i] >> 17], 1);
    }
    __syncthreads();
    for (int t = threadIdx.x; t < hi - lo; t += 1024)
        deg[lo + t] = ldeg[t];                  // coalesced full-line write, once
}

// ---------------- phase 2: scatter into CSR with per-range LDS cursors ----------------
__global__ __launch_bounds__(1024) void k_scatter2(const unsigned int* __restrict__ pairs,
                                                   const int* __restrict__ pcur,
                                                   const int* __restrict__ row_start,
                                                   int* __restrict__ csr_src) {
    __shared__ int lcur[RSIZE];
    const int r = blockIdx.x;                   // 0..63; XCD = r%8
    const int lo = r * RSIZE;
    for (int t = threadIdx.x; t < RSIZE; t += 1024) lcur[t] = 0;
    __syncthreads();
    for (int p = 0; p < 8; ++p) {
        int b = (p << 6) | r;
        int len = pcur[b];
        if (len > CAP) len = CAP;
        const unsigned int* base = pairs + (size_t)b * CAP;
        for (int i = threadIdx.x; i < len; i += 1024) {
            unsigned int pk = base[i];
            int dloc = pk >> 17;
            int lp = atomicAdd(&lcur[dloc], 1);             // LDS atomic
            csr_src[row_start[lo + dloc] + lp] = (int)(pk & 0x1FFFFu);
        }
    }
}

// ---------------- hierarchical scan: block sums ----------------
__global__ __launch_bounds__(256) void k_bsum(const int* __restrict__ deg, int* __restrict__ bsum) {
    int i = blockIdx.x * 256 + threadIdx.x;
    int v = (i < NN) ? deg[i] : 0;
    int lane = threadIdx.x & 63, wid = threadIdx.x >> 6;
#pragma unroll
    for (int d = 32; d; d >>= 1) v += __shfl_down(v, d, 64);
    __shared__ int wsum[4];
    if (lane == 0) wsum[wid] = v;
    __syncthreads();
    if (threadIdx.x == 0) bsum[blockIdx.x] = wsum[0] + wsum[1] + wsum[2] + wsum[3];
}

// ---------------- scan of 391 block sums (one block) ----------------
__global__ __launch_bounds__(512) void k_bscan(const int* __restrict__ bsum, int* __restrict__ boff,
                                               int* __restrict__ row_start) {
    __shared__ int s[512];
    int tid = threadIdx.x;
    int v = (tid < NB) ? bsum[tid] : 0;
    s[tid] = v;
    __syncthreads();
    for (int d = 1; d < 512; d <<= 1) {
        int t = (tid >= d) ? s[tid - d] : 0;
        __syncthreads();
        s[tid] += t;
        __syncthreads();
    }
    if (tid < NB) boff[tid] = s[tid] - v;   // exclusive
    if (tid == 0) row_start[NN] = EE;
}

// ---------------- final scan: row_start + deg_inv ----------------
__global__ __launch_bounds__(256) void k_scan2(const int* __restrict__ deg, const int* __restrict__ boff,
                                               int* __restrict__ row_start, float* __restrict__ deg_inv) {
    int tid = threadIdx.x, lane = tid & 63, wid = tid >> 6;
    int i = blockIdx.x * 256 + tid;
    int v = (i < NN) ? deg[i] : 0;
    int inc = v;
#pragma unroll
    for (int d = 1; d < 64; d <<= 1) {
        int t = __shfl_up(inc, d, 64);
        if (lane >= d) inc += t;
    }
    __shared__ int wsum[4];
    if (lane == 63) wsum[wid] = inc;
    __syncthreads();
    if (tid == 0) {
        int s = 0;
#pragma unroll
        for (int j = 0; j < 4; ++j) { int t = wsum[j]; wsum[j] = s; s += t; }
    }
    __syncthreads();
    if (i < NN) {
        row_start[i] = boff[blockIdx.x] + wsum[wid] + (inc - v);
        deg_inv[i] = (v > 0) ? 1.0f / (float)v : 0.0f;
    }
}

// ---------------- bf16 mean-aggregate into mean buffer (NN x 64, zero-padded) ----------------
template<int Fin>
__global__ __launch_bounds__(256) void k_meanb(const unsigned short* __restrict__ xin,
                                               const int* __restrict__ row_start,
                                               const int* __restrict__ csr_src,
                                               const float* __restrict__ deg_inv,
                                               unsigned short* __restrict__ meanb) {
    constexpr int CH = Fin / 8;     // data chunks (5 or 8)
    int gid = blockIdx.x * 256 + threadIdx.x;
    int node = gid >> 3;
    int c = gid & 7;
    if (node >= NN) return;
    float acc[8] = {0, 0, 0, 0, 0, 0, 0, 0};
    if (c < CH) {
        const unsigned short* xq = xin + c * 8;
        int rs = row_start[node], re = row_start[node + 1];
        int k = rs;
        for (; k + 4 <= re; k += 4) {
            int s0 = csr_src[k], s1 = csr_src[k + 1], s2 = csr_src[k + 2], s3 = csr_src[k + 3];
            short8 v0 = *(const short8*)(xq + (size_t)s0 * Fin);
            short8 v1 = *(const short8*)(xq + (size_t)s1 * Fin);
            short8 v2 = *(const short8*)(xq + (size_t)s2 * Fin);
            short8 v3 = *(const short8*)(xq + (size_t)s3 * Fin);
#pragma unroll
            for (int j = 0; j < 8; ++j)
                acc[j] += (bf2f((unsigned short)v0[j]) + bf2f((unsigned short)v1[j]))
                        + (bf2f((unsigned short)v2[j]) + bf2f((unsigned short)v3[j]));
        }
        for (; k < re; ++k) {
            short8 v0 = *(const short8*)(xq + (size_t)csr_src[k] * Fin);
#pragma unroll
            for (int j = 0; j < 8; ++j) acc[j] += bf2f((unsigned short)v0[j]);
        }
        float di = deg_inv[node];
#pragma unroll
        for (int j = 0; j < 8; ++j) acc[j] *= di;
    }
    short8 m;
#pragma unroll
    for (int j = 0; j < 8; ++j) m[j] = (c < CH) ? (short)f2bf(acc[j]) : (short)0;
    *(short8*)(meanb + (size_t)node * 64 + c * 8) = m;
}

// ---------------- MFMA GEMM: out = relu?(mean@Wl^T + root@Wr^T + b) ----------------
// K = 128 (mean 64-padded | root 64-padded); root read DIRECTLY from xb/h1
// (stride Fin), zero chunks where k >= Fin. B frags: k<64 -> Wl, else Wr.
template<int Fin, int Fout, bool RELU>
__global__ __launch_bounds__(256) void k_gemm(const unsigned short* __restrict__ meanb,
                                              const unsigned short* __restrict__ root,
                                              const float* __restrict__ Wl,
                                              const float* __restrict__ bias,
                                              const float* __restrict__ Wr,
                                              unsigned short* __restrict__ out) {
    constexpr int KS = 4;                       // 2 mean + 2 root
    constexpr int TILES = Fout / 16;
    __shared__ short sB[TILES * KS * 64 * 8];
    const int lane = threadIdx.x & 63;
    for (int idx = threadIdx.x; idx < TILES * KS * 64; idx += 256) {
        int l = idx & 63;
        int ks = (idx >> 6) % KS;
        int t = idx / (64 * KS);
        int o = t * 16 + (l & 15);
        int kbase = ks * 32 + (l >> 4) * 8;
        short8 v;
#pragma unroll
        for (int j = 0; j < 8; ++j) {
            int k = kbase + j;
            float w;
            if (k < 64) w = (k < Fin) ? Wl[(size_t)o * Fin + k] : 0.f;
            else { int k2 = k - 64; w = (k2 < Fin) ? Wr[(size_t)o * Fin + k2] : 0.f; }
            v[j] = (short)f2bf(w);
        }
        *(short8*)&sB[idx * 8] = v;
    }
    __syncthreads();
    float bias_t[TILES];
#pragma unroll
    for (int t = 0; t < TILES; ++t) bias_t[t] = bias[t * 16 + (lane & 15)];

    const int kchunk = (lane >> 4) * 8;         // 0,8,16,24 within a 32-wide ks step
    const int wave = blockIdx.x * 4 + (threadIdx.x >> 6);
    const int nchunks = NN / 32;                // 3125
    for (int ci = wave; ci < nchunks; ci += gridDim.x * 4) {
        int nbase = ci * 32;
        int row0 = nbase + (lane & 15);
        const unsigned short* m0 = meanb + (size_t)row0 * 64 + kchunk;
        const unsigned short* r0 = root + (size_t)row0 * Fin + kchunk;
        short8 af[2][KS];
#pragma unroll
        for (int ks = 0; ks < 2; ++ks) {        // mean halves (always valid: 64-padded)
            af[0][ks] = *(const short8*)(m0 + ks * 32);
            af[1][ks] = *(const short8*)(m0 + 16 * 64 + ks * 32);
        }
#pragma unroll
        for (int ks = 0; ks < 2; ++ks) {        // root halves (guard k >= Fin chunks)
            int k2 = ks * 32 + kchunk;
            if (k2 + 8 <= Fin) {
                af[0][2 + ks] = *(const short8*)(r0 + ks * 32);
                af[1][2 + ks] = *(const short8*)(r0 + (size_t)16 * Fin + ks * 32);
            } else {
                short8 zz = {0, 0, 0, 0, 0, 0, 0, 0};
                af[0][2 + ks] = zz;
                af[1][2 + ks] = zz;
            }
        }
        f32x4 acc[2][TILES];
#pragma unroll
        for (int m = 0; m < 2; ++m)
#pragma unroll
            for (int t = 0; t < TILES; ++t) acc[m][t] = (f32x4){0.f, 0.f, 0.f, 0.f};
#pragma unroll
        for (int t = 0; t < TILES; ++t)
#pragma unroll
            for (int ks = 0; ks < KS; ++ks) {
                short8 bf = *(const short8*)&sB[((t * KS + ks) * 64 + lane) * 8];
                acc[0][t] = __builtin_amdgcn_mfma_f32_16x16x32_bf16(af[0][ks], bf, acc[0][t], 0, 0, 0);
                acc[1][t] = __builtin_amdgcn_mfma_f32_16x16x32_bf16(af[1][ks], bf, acc[1][t], 0, 0, 0);
            }
#pragma unroll
        for (int m = 0; m < 2; ++m) {
            int nrow = nbase + m * 16 + (lane >> 4) * 4;
#pragma unroll
            for (int t = 0; t < TILES; ++t) {
                int col = t * 16 + (lane & 15);
#pragma unroll
                for (int r = 0; r < 4; ++r) {
                    float v = acc[m][t][r] + bias_t[t];
                    if (RELU) v = fmaxf(v, 0.f);
                    out[(size_t)(nrow + r) * Fout + col] = f2bf(v);
                }
            }
        }
    }
}

// ---------------- layer 3 transform via narrow MFMA: [z|r] = h2 @ B (128x16) ----------------
__global__ __launch_bounds__(256) void k_zr_mfma(const unsigned short* __restrict__ h2,
                                                 const float* __restrict__ W4l, const float* __restrict__ W4r,
                                                 float* __restrict__ z, float* __restrict__ r) {
    __shared__ short sB[4 * 64 * 8];           // 4 ks-frags
    {
        int idx = threadIdx.x;                 // 256 = 4*64 entries exactly
        int l = idx & 63;
        int ks = idx >> 6;
        int o = l & 15;
        int kbase = ks * 32 + (l >> 4) * 8;
        short8 v;
#pragma unroll
        for (int j = 0; j < 8; ++j) {
            int k = kbase + j;
            float w = 0.f;
            if (o < 3) w = W4l[o * 128 + k];
            else if (o >= 4 && o < 7) w = W4r[(o - 4) * 128 + k];
            v[j] = (short)f2bf(w);
        }
        *(short8*)&sB[idx * 8] = v;
    }
    __syncthreads();
    const int lane = threadIdx.x & 63;
    short8 bf[4];
#pragma unroll
    for (int ks = 0; ks < 4; ++ks) bf[ks] = *(const short8*)&sB[(ks * 64 + lane) * 8];

    const int col = lane & 15;
    const int rbase = (lane >> 4) * 4;
    const int wave = blockIdx.x * 4 + (threadIdx.x >> 6);
    const int nchunks = NN / 32;               // 3125
    for (int ci = wave; ci < nchunks; ci += gridDim.x * 4) {
        int nbase = ci * 32;
        const unsigned short* a0 = h2 + (size_t)(nbase + (lane & 15)) * 128 + (lane >> 4) * 8;
        f32x4 acc0 = (f32x4){0.f, 0.f, 0.f, 0.f};
        f32x4 acc1 = (f32x4){0.f, 0.f, 0.f, 0.f};
#pragma unroll
        for (int ks = 0; ks < 4; ++ks) {
            short8 af0 = *(const short8*)(a0 + ks * 32);
            short8 af1 = *(const short8*)(a0 + 16 * 128 + ks * 32);
            acc0 = __builtin_amdgcn_mfma_f32_16x16x32_bf16(af0, bf[ks], acc0, 0, 0, 0);
            acc1 = __builtin_amdgcn_mfma_f32_16x16x32_bf16(af1, bf[ks], acc1, 0, 0, 0);
        }
#pragma unroll
        for (int m = 0; m < 2; ++m) {
            f32x4 a = m ? acc1 : acc0;
            int nr = nbase + m * 16 + rbase;
            if (col < 3) {
#pragma unroll
                for (int q = 0; q < 4; ++q) z[(size_t)(nr + q) * 4 + col] = a[q];
            } else if (col >= 4 && col < 7) {
#pragma unroll
                for (int q = 0; q < 4; ++q) r[(size_t)(nr + q) * 4 + col - 4] = a[q];
            }
        }
    }
}

// ---------------- final: out = mean(z)[n] + r[n] + b4 ----------------
__global__ __launch_bounds__(256) void k_final(const float* __restrict__ z, const float* __restrict__ r,
                                               const float* __restrict__ b4,
                                               const int* __restrict__ row_start, const int* __restrict__ csr_src,
                                               const float* __restrict__ deg_inv, float* __restrict__ out) {
    int n = blockIdx.x * 256 + threadIdx.x;
    if (n >= NN) return;
    int rs = row_start[n], re = row_start[n + 1];
    float a0 = 0, a1 = 0, a2 = 0, b0 = 0, b1 = 0, b2 = 0;
    int k = rs;
    for (; k + 4 <= re; k += 4) {
        int s0 = csr_src[k], s1 = csr_src[k + 1], s2 = csr_src[k + 2], s3 = csr_src[k + 3];
        float4 z0 = *(const float4*)&z[4 * (size_t)s0];
        float4 z1 = *(const float4*)&z[4 * (size_t)s1];
        float4 z2 = *(const float4*)&z[4 * (size_t)s2];
        float4 z3 = *(const float4*)&z[4 * (size_t)s3];
        a0 += z0.x; a1 += z0.y; a2 += z0.z;
        b0 += z1.x; b1 += z1.y; b2 += z1.z;
        a0 += z2.x; a1 += z2.y; a2 += z2.z;
        b0 += z3.x; b1 += z3.y; b2 += z3.z;
    }
    for (; k < re; ++k) {
        float4 z0 = *(const float4*)&z[4 * (size_t)csr_src[k]];
        a0 += z0.x; a1 += z0.y; a2 += z0.z;
    }
    float di = deg_inv[n];
    float4 rn = *(const float4*)&r[4 * (size_t)n];
    out[(size_t)n * 3 + 0] = (a0 + b0) * di + rn.x + b4[0];
    out[(size_t)n * 3 + 1] = (a1 + b1) * di + rn.y + b4[1];
    out[(size_t)n * 3 + 2] = (a2 + b2) * di + rn.z + b4[2];
}

extern "C" void kernel_launch(void* const* d_in, const int* in_sizes, int n_in,
                              void* d_out, int out_size, void* d_ws, size_t ws_size,
                              hipStream_t stream) {
    const float* x   = (const float*)d_in[0];
    const int*   ei  = (const int*)d_in[1];
    const float* W1l = (const float*)d_in[2];
    const float* b1  = (const float*)d_in[3];
    const float* W1r = (const float*)d_in[4];
    const float* W2l = (const float*)d_in[5];
    const float* b2  = (const float*)d_in[6];
    const float* W2r = (const float*)d_in[7];
    const float* W4l = (const float*)d_in[8];
    const float* b4  = (const float*)d_in[9];
    const float* W4r = (const float*)d_in[10];
    float* out = (float*)d_out;

    char* ws = (char*)d_ws;
    size_t off = 0;
    auto alloc = [&](size_t bytes) -> void* {
        void* p = ws + off;
        off = (off + bytes + 255) & ~(size_t)255;
        return p;
    };
    int*   deg       = (int*)alloc((size_t)NN * 4);
    int*   row_start = (int*)alloc(((size_t)NN + 1) * 4);
    int*   csr_src   = (int*)alloc((size_t)EE * 4);
    float* deg_inv   = (float*)alloc((size_t)NN * 4);
    int*   bsum      = (int*)alloc((size_t)NB * 4);
    int*   boff      = (int*)alloc((size_t)NB * 4);
    int*   pcur      = (int*)alloc((size_t)NBUCKET * 4);
    unsigned short* xb    = (unsigned short*)alloc((size_t)NN * 40 * 2);
    unsigned short* meanb = (unsigned short*)alloc((size_t)NN * 64 * 2);   // 12.8 MB, reused L1+L2
    unsigned short* h1    = (unsigned short*)alloc((size_t)NN * 64 * 2);
    unsigned short* h2    = (unsigned short*)alloc((size_t)NN * 128 * 2);  // 25.6 MB
    float* zbuf = (float*)alloc((size_t)NN * 4 * 4);
    float* rbuf = (float*)alloc((size_t)NN * 4 * 4);
    // pairs (8.4 MB) aliases h2 (25.6 MB): dead before h2 first written (L2 gemm)
    unsigned int* pairs = (unsigned int*)h2;

    const int* e_src = ei;
    const int* e_dst = ei + EE;

    hipMemsetAsync(pcur, 0, (size_t)NBUCKET * 4, stream);

    // phase 1: bucket (packed, block-local reservation) + x->bf16, one dispatch
    k_bucket_cvt<<<BUCKET_BLOCKS + CVT_BLOCKS, 256, 0, stream>>>(e_src, e_dst, pcur, pairs, x, xb);
    // phase 1.5: per-range LDS degree count
    k_degr<<<NRANGE, 1024, 0, stream>>>(pairs, pcur, deg);
    k_bsum<<<NB, 256, 0, stream>>>(deg, bsum);
    k_bscan<<<1, 512, 0, stream>>>(bsum, boff, row_start);
    k_scan2<<<NB, 256, 0, stream>>>(deg, boff, row_start, deg_inv);
    // phase 2: scatter with per-range LDS cursors
    k_scatter2<<<NRANGE, 1024, 0, stream>>>(pairs, pcur, row_start, csr_src);

    const int mean_blocks = ((size_t)NN * 8 + 255) / 256;   // 3125
    const int gemm_blocks = 782;

    // layer 1: 40 -> 64
    k_meanb<40><<<mean_blocks, 256, 0, stream>>>(xb, row_start, csr_src, deg_inv, meanb);
    k_gemm<40, 64, true><<<gemm_blocks, 256, 0, stream>>>(meanb, xb, W1l, b1, W1r, h1);

    // layer 2: 64 -> 128
    k_meanb<64><<<mean_blocks, 256, 0, stream>>>(h1, row_start, csr_src, deg_inv, meanb);
    k_gemm<64, 128, true><<<gemm_blocks, 256, 0, stream>>>(meanb, h1, W2l, b2, W2r, h2);

    // layer 3: 128 -> 3, transform-before-gather (narrow MFMA)
    k_zr_mfma<<<gemm_blocks, 256, 0, stream>>>(h2, W4l, W4r, zbuf, rbuf);
    k_final<<<(NN + 255) / 256, 256, 0, stream>>>(zbuf, rbuf, b4, row_start, csr_src, deg_inv, out);
}